// Round 2
// 346.426 us; speedup vs baseline: 1.0944x; 1.0944x over previous
//
#include <hip/hip_runtime.h>

// ProteinGCN: 2x GCNConv(+relu) + FC head. N=100k, E=1.6M, 64->128->64->1.
// Round 7: same split-bf16 MFMA gemm12 as round 6; W-split buffers now alias
// the dead `cnt` buffer (64 KB into its 400 KB) so the workspace footprint is
// byte-identical to the verified 381us kernel -- round 6's container crash is
// consistent with a ws_size overflow from the 4 appended weight buffers.
// Rationale (round 6): k_gemm12 was top dispatch (70 us) at MfmaUtil=0,
// VALU 37%, occ 24% -- fp32 VALU GEMM latency-bound on weight reloads.
// Split-bf16 (hi+lo) MFMA: 3x mfma_f32_16x16x32_bf16 per fp32 product
// (Ah*Bh + Ah*Bl + Al*Bh; dropped term ~2^-18 rel). Weights pre-split into
// B-fragment order once (coalesced 16B/lane loads). A-fragments straight
// from global; h1 in LDS packed (hi|lo<<16), stride 132. One barrier.

constexpr int NN = 100000;
constexpr int NE = 1600000;
constexpr int D0 = 64;   // input dim
constexpr int D1 = 128;  // hidden 1
constexpr int D2 = 64;   // hidden 2
constexpr int NB = (NN + 255) / 256;  // 391 buckets
constexpr int TILE = 8192;            // edges per k_part block
constexpr int H1STRIDE = 132;         // h1 LDS row stride (u32)

typedef unsigned short u16;
typedef unsigned int u32;
typedef __attribute__((ext_vector_type(8))) short short8;  // 8 bf16 (4 VGPR)
typedef __attribute__((ext_vector_type(4))) float f32x4;

// ---------------- CSR build ----------------

__global__ __launch_bounds__(256) void k_zero_cnt(int* __restrict__ cnt) {
    int i = blockIdx.x * 256 + threadIdx.x;
    if (i < NN) cnt[i] = 0;
}

__global__ __launch_bounds__(256) void k_hist(const int* __restrict__ dst,
                                              int* __restrict__ cnt) {
    int e = blockIdx.x * 256 + threadIdx.x;
    if (e < NE) atomicAdd(&cnt[dst[e]], 1);
}

__global__ __launch_bounds__(256) void k_scan_block(const int* __restrict__ cnt,
                                                    int* __restrict__ rowptr,
                                                    int* __restrict__ bsum) {
    __shared__ int s[256];
    int tid = threadIdx.x;
    int i = blockIdx.x * 256 + tid;
    int v = (i < NN) ? cnt[i] : 0;
    s[tid] = v;
    __syncthreads();
#pragma unroll
    for (int off = 1; off < 256; off <<= 1) {
        int t = (tid >= off) ? s[tid - off] : 0;
        __syncthreads();
        s[tid] += t;
        __syncthreads();
    }
    if (i < NN) rowptr[i] = s[tid] - v;  // exclusive
    if (tid == 255) bsum[blockIdx.x] = s[255];
}

__global__ __launch_bounds__(512) void k_scan_bsum(int* __restrict__ bsum,
                                                   int* __restrict__ gcur) {
    __shared__ int s[512];
    int tid = threadIdx.x;
    int v = (tid < NB) ? bsum[tid] : 0;
    s[tid] = v;
    __syncthreads();
#pragma unroll
    for (int off = 1; off < 512; off <<= 1) {
        int t = (tid >= off) ? s[tid - off] : 0;
        __syncthreads();
        s[tid] += t;
        __syncthreads();
    }
    int ex = s[tid] - v;  // exclusive scan
    if (tid <= NB) bsum[tid] = ex;   // bsum[NB] == NE
    if (tid < NB) gcur[tid] = ex;
}

__global__ __launch_bounds__(256) void k_scan_add(int* __restrict__ rowptr,
                                                  const int* __restrict__ bsum) {
    int i = blockIdx.x * 256 + threadIdx.x;
    if (i < NN) rowptr[i] += bsum[i >> 8];
    if (i == 0) rowptr[NN] = NE;
}

__global__ __launch_bounds__(256) void k_dinv(const int* __restrict__ cnt,
                                              float* __restrict__ dinv) {
    int i = blockIdx.x * 256 + threadIdx.x;
    if (i < NN) dinv[i] = rsqrtf((float)(cnt[i] + 1));
}

// ---- phase 1: partition edges into dst-buckets, packed (dl<<24)|src ----
__global__ __launch_bounds__(256) void k_part(const int* __restrict__ src,
                                              const int* __restrict__ dst,
                                              int* __restrict__ gcur,
                                              unsigned* __restrict__ packed) {
    __shared__ int cnt_s[NB];
    __shared__ int gbase_s[NB];
    __shared__ int cur_s[NB];
    int tid = threadIdx.x;
    int e0 = blockIdx.x * TILE;
    int ecnt = NE - e0 < TILE ? NE - e0 : TILE;
    for (int i = tid; i < NB; i += 256) cnt_s[i] = 0;
    __syncthreads();
    for (int i = tid; i < ecnt; i += 256)
        atomicAdd(&cnt_s[dst[e0 + i] >> 8], 1);
    __syncthreads();
    for (int i = tid; i < NB; i += 256) {
        int c = cnt_s[i];
        gbase_s[i] = c ? atomicAdd(&gcur[i], c) : 0;
        cur_s[i] = 0;
    }
    __syncthreads();
    for (int i = tid; i < ecnt; i += 256) {
        int d = dst[e0 + i];
        int s = src[e0 + i];
        int b = d >> 8;
        int slot = atomicAdd(&cur_s[b], 1);
        packed[gbase_s[b] + slot] = ((unsigned)(d & 255) << 24) | (unsigned)s;
    }
}

// ---- phase 2: one block per bucket, LDS node cursors, local col writes ----
__global__ __launch_bounds__(256) void k_fill2(const int* __restrict__ bsum,
                                               const int* __restrict__ rowptr,
                                               const unsigned* __restrict__ packed,
                                               int* __restrict__ col) {
    __shared__ int cur[256];
    int b = blockIdx.x;
    int n = (b << 8) + threadIdx.x;
    cur[threadIdx.x] = rowptr[n <= NN ? n : NN];
    __syncthreads();
    int e1 = bsum[b + 1];
    for (int e = bsum[b] + threadIdx.x; e < e1; e += 256) {
        unsigned p = packed[e];
        int pos = atomicAdd(&cur[p >> 24], 1);
        col[pos] = (int)(p & 0xFFFFFFu);
    }
}

// ---------------- helpers ----------------

__device__ __forceinline__ float4 scale4(const float4& a, float s) {
    return float4{a.x * s, a.y * s, a.z * s, a.w * s};
}

__device__ __forceinline__ void add4(float4& a, const float4& b) {
    a.x += b.x; a.y += b.y; a.z += b.z; a.w += b.w;
}

__device__ __forceinline__ void xor_reduce4(float4& a, int mask) {
    a.x += __shfl_xor(a.x, mask, 64);
    a.y += __shfl_xor(a.y, mask, 64);
    a.z += __shfl_xor(a.z, mask, 64);
    a.w += __shfl_xor(a.w, mask, 64);
}

// bf16 RNE conversion + back
__device__ __forceinline__ u16 f2bf(float f) {
    u32 u = __float_as_uint(f);
    return (u16)((u + 0x7fffu + ((u >> 16) & 1u)) >> 16);
}
__device__ __forceinline__ float bf2f(u16 h) {
    return __uint_as_float(((u32)h) << 16);
}

// ---------------- prescale: xs = x * dinv ----------------
__global__ __launch_bounds__(256) void k_prescale(const float* __restrict__ x,
                                                  const float* __restrict__ dinv,
                                                  float* __restrict__ xs) {
    int i = blockIdx.x * 256 + threadIdx.x;  // float4 index
    if (i >= NN * 16) return;
    float di = dinv[i >> 4];
    ((float4*)xs)[i] = scale4(((const float4*)x)[i], di);
}

// ---------------- layer-1 gather on prescaled xs ----------------
// agg[d] = dinv_d * ( xs[d] + sum_{s in in(d)} xs[s] )
__global__ __launch_bounds__(256) void k_gather1x(const int* __restrict__ rowptr,
                                                  const int* __restrict__ col,
                                                  const float* __restrict__ xs,
                                                  const float* __restrict__ dinv,
                                                  float* __restrict__ agg) {
    int wave = (blockIdx.x * 256 + threadIdx.x) >> 6;
    int lane = threadIdx.x & 63;
    if (wave >= NN) return;
    int f4 = lane & 15;   // float4 index within 64-float row
    int es = lane >> 4;   // edge sublane 0..3
    int r0 = rowptr[wave], r1 = rowptr[wave + 1];
    const float4* xs4 = (const float4*)xs;
    float4 acc{0, 0, 0, 0};
    if (es == 0) acc = xs4[(size_t)wave * 16 + f4];  // self loop (once)
    int e = r0 + es;
    for (; e + 4 < r1; e += 8) {
        int s0 = col[e];
        int s1 = col[e + 4];
        float4 v0 = xs4[(size_t)s0 * 16 + f4];
        float4 v1 = xs4[(size_t)s1 * 16 + f4];
        add4(acc, v0);
        add4(acc, v1);
    }
    for (; e < r1; e += 4) {
        float4 v = xs4[(size_t)col[e] * 16 + f4];
        add4(acc, v);
    }
    xor_reduce4(acc, 16);
    xor_reduce4(acc, 32);
    if (es == 0)
        ((float4*)agg)[(size_t)wave * 16 + f4] = scale4(acc, dinv[wave]);
}

// ---------------- weight pre-split into MFMA B-fragment order ----------------
// B-fragment (16x16x32 bf16): lane l holds B[k][col], col=l&15, k=(l>>4)*8+j.
// W1 frags: [(s*8+t)*64 + l]*8 + j  (s: k-step 0..1, t: n-tile 0..7)
// W2 frags: [(s*4+t)*64 + l]*8 + j  (s: k-step 0..3, t: n-tile 0..3)
__global__ __launch_bounds__(256) void k_splitW(const float* __restrict__ W1,
                                                const float* __restrict__ W2,
                                                u16* __restrict__ W1h, u16* __restrict__ W1l,
                                                u16* __restrict__ W2h, u16* __restrict__ W2l) {
    int i = blockIdx.x * 256 + threadIdx.x;  // 0..8191
    if (i >= 8192) return;
    int j = i & 7;
    int l = (i >> 3) & 63;
    int ts = i >> 9;                 // 0..15
    int kf = ((l >> 4) << 3) + j;    // k within 32-step
    int cl = l & 15;
    {   // W1 [64][128]: ts = s*8 + t
        int s = ts >> 3, t = ts & 7;
        float w = W1[(s * 32 + kf) * D1 + t * 16 + cl];
        u16 h = f2bf(w);
        W1h[i] = h;
        W1l[i] = f2bf(w - bf2f(h));
    }
    {   // W2 [128][64]: ts = s*4 + t
        int s = ts >> 2, t = ts & 3;
        float w = W2[(s * 32 + kf) * D2 + t * 16 + cl];
        u16 h = f2bf(w);
        W2h[i] = h;
        W2l[i] = f2bf(w - bf2f(h));
    }
}

// ---------------- fused GEMM1 + GEMM2 via split-bf16 MFMA ----------------
// h1 = relu(agg @ W1 + b1)   (64 -> 128, packed hi/lo bf16 in LDS)
// y2 = (h1 @ W2) * dinv      (128 -> 64)
// Block: 64 nodes, 4 waves; wave w owns node rows w*16..w*16+15.
__global__ __launch_bounds__(256) void k_gemm12(const float* __restrict__ agg,
                                                const u16* __restrict__ W1h,
                                                const u16* __restrict__ W1l,
                                                const float* __restrict__ b1,
                                                const u16* __restrict__ W2h,
                                                const u16* __restrict__ W2l,
                                                const float* __restrict__ dinv,
                                                float* __restrict__ y2) {
    __shared__ u32 h1s[64 * H1STRIDE];  // packed (hi | lo<<16), 33.8 KB
    int tid = threadIdx.x;
    int l = tid & 63;
    int wv = tid >> 6;
    int n_base = blockIdx.x * 64;
    int row_a = l & 15;           // A-operand row within 16-tile
    int kg = (l >> 4) << 3;       // k offset within 32-step: 0,8,16,24
    int crow = (l >> 4) * 4;      // C/D row base: (lane>>4)*4

    // ---- phase A: h1 = relu(agg @ W1 + b1) ----
    short8 Ah[2], Al[2];
#pragma unroll
    for (int s = 0; s < 2; ++s) {
        int an = n_base + wv * 16 + row_a;
        if (an >= NN) an = NN - 1;  // clamp: dup rows, outputs discarded
        const float* ap = agg + (size_t)an * D0 + s * 32 + kg;
        f32x4 v0 = *(const f32x4*)ap;
        f32x4 v1 = *(const f32x4*)(ap + 4);
#pragma unroll
        for (int j = 0; j < 4; ++j) {
            u16 h0 = f2bf(v0[j]);
            Ah[s][j] = (short)h0;
            Al[s][j] = (short)f2bf(v0[j] - bf2f(h0));
            u16 h1b = f2bf(v1[j]);
            Ah[s][j + 4] = (short)h1b;
            Al[s][j + 4] = (short)f2bf(v1[j] - bf2f(h1b));
        }
    }
#pragma unroll
    for (int t = 0; t < 8; ++t) {
        f32x4 acc = {0.f, 0.f, 0.f, 0.f};
#pragma unroll
        for (int s = 0; s < 2; ++s) {
            short8 Bh = *(const short8*)(W1h + ((size_t)(s * 8 + t) * 64 + l) * 8);
            short8 Bl = *(const short8*)(W1l + ((size_t)(s * 8 + t) * 64 + l) * 8);
            acc = __builtin_amdgcn_mfma_f32_16x16x32_bf16(Ah[s], Bh, acc, 0, 0, 0);
            acc = __builtin_amdgcn_mfma_f32_16x16x32_bf16(Ah[s], Bl, acc, 0, 0, 0);
            acc = __builtin_amdgcn_mfma_f32_16x16x32_bf16(Al[s], Bh, acc, 0, 0, 0);
        }
        // epilogue: +b1, relu, split-pack to LDS (C/D: row=(l>>4)*4+r, col=l&15)
        float bb = b1[t * 16 + (l & 15)];
        int kcol = t * 16 + (l & 15);  // h1 feature index = GEMM2 k
#pragma unroll
        for (int r = 0; r < 4; ++r) {
            int row = wv * 16 + crow + r;  // node row in 64-tile
            float v = fmaxf(acc[r] + bb, 0.f);
            u16 h = f2bf(v);
            u16 lo = f2bf(v - bf2f(h));
            h1s[row * H1STRIDE + kcol] = (u32)h | ((u32)lo << 16);
        }
    }
    __syncthreads();

    // ---- phase B: y2 = (h1 @ W2) * dinv ----
    short8 A2h[4], A2l[4];
#pragma unroll
    for (int s = 0; s < 4; ++s) {
        int row = wv * 16 + row_a;
        const u32* hp = &h1s[row * H1STRIDE + s * 32 + kg];
        uint4 p0 = *(const uint4*)hp;
        uint4 p1 = *(const uint4*)(hp + 4);
        u32 pv[8] = {p0.x, p0.y, p0.z, p0.w, p1.x, p1.y, p1.z, p1.w};
#pragma unroll
        for (int j = 0; j < 8; ++j) {
            A2h[s][j] = (short)(pv[j] & 0xffffu);
            A2l[s][j] = (short)(pv[j] >> 16);
        }
    }
#pragma unroll
    for (int t = 0; t < 4; ++t) {
        f32x4 acc = {0.f, 0.f, 0.f, 0.f};
#pragma unroll
        for (int s = 0; s < 4; ++s) {
            short8 Bh = *(const short8*)(W2h + ((size_t)(s * 4 + t) * 64 + l) * 8);
            short8 Bl = *(const short8*)(W2l + ((size_t)(s * 4 + t) * 64 + l) * 8);
            acc = __builtin_amdgcn_mfma_f32_16x16x32_bf16(A2h[s], Bh, acc, 0, 0, 0);
            acc = __builtin_amdgcn_mfma_f32_16x16x32_bf16(A2h[s], Bl, acc, 0, 0, 0);
            acc = __builtin_amdgcn_mfma_f32_16x16x32_bf16(A2l[s], Bh, acc, 0, 0, 0);
        }
#pragma unroll
        for (int r = 0; r < 4; ++r) {
            int n = n_base + wv * 16 + crow + r;
            if (n < NN) y2[(size_t)n * D2 + t * 16 + (l & 15)] = acc[r] * dinv[n];
        }
    }
}

// ---------------- layer-2 gather fused with FC head ----------------
// acc = y2[d] + sum y2[s]; out[d] = relu(acc*dinv_d + b2) . Wfc + bfc
__global__ __launch_bounds__(256) void k_gather2_final(const int* __restrict__ rowptr,
                                                       const int* __restrict__ col,
                                                       const float* __restrict__ y2,
                                                       const float* __restrict__ dinv,
                                                       const float* __restrict__ b2,
                                                       const float* __restrict__ Wfc,
                                                       const float* __restrict__ bfc,
                                                       float* __restrict__ out) {
    int wave = (blockIdx.x * 256 + threadIdx.x) >> 6;
    int lane = threadIdx.x & 63;
    if (wave >= NN) return;
    int f4 = lane & 15;
    int es = lane >> 4;
    int r0 = rowptr[wave], r1 = rowptr[wave + 1];
    const float4* y24 = (const float4*)y2;
    float4 acc{0, 0, 0, 0};
    if (es == 0) acc = y24[(size_t)wave * 16 + f4];  // self loop (once)
    int e = r0 + es;
    for (; e + 4 < r1; e += 8) {
        int s0 = col[e];
        int s1 = col[e + 4];
        float4 v0 = y24[(size_t)s0 * 16 + f4];
        float4 v1 = y24[(size_t)s1 * 16 + f4];
        add4(acc, v0);
        add4(acc, v1);
    }
    for (; e < r1; e += 4) {
        float4 v = y24[(size_t)col[e] * 16 + f4];
        add4(acc, v);
    }
    xor_reduce4(acc, 16);
    xor_reduce4(acc, 32);
    // every lane now holds the feature-group sum for its f4 (4 copies)
    float di = dinv[wave];
    float4 b = ((const float4*)b2)[f4];
    float4 w = ((const float4*)Wfc)[f4];
    float p = fmaxf(fmaf(acc.x, di, b.x), 0.f) * w.x
            + fmaxf(fmaf(acc.y, di, b.y), 0.f) * w.y
            + fmaxf(fmaf(acc.z, di, b.z), 0.f) * w.z
            + fmaxf(fmaf(acc.w, di, b.w), 0.f) * w.w;
    // sum the 16 f4 groups (each 16-lane block holds all 16 f4 values)
    p += __shfl_xor(p, 1, 64);
    p += __shfl_xor(p, 2, 64);
    p += __shfl_xor(p, 4, 64);
    p += __shfl_xor(p, 8, 64);
    if (lane == 0) out[wave] = p + bfc[0];
}

extern "C" void kernel_launch(void* const* d_in, const int* in_sizes, int n_in,
                              void* d_out, int out_size, void* d_ws, size_t ws_size,
                              hipStream_t stream) {
    const float* x   = (const float*)d_in[0];
    const int*   ei  = (const int*)d_in[1];   // [2, E] int
    const float* W1  = (const float*)d_in[2];
    const float* b1  = (const float*)d_in[3];
    const float* W2  = (const float*)d_in[4];
    const float* b2  = (const float*)d_in[5];
    const float* Wfc = (const float*)d_in[6];
    const float* bfc = (const float*)d_in[7];
    float* out = (float*)d_out;

    const int* src = ei;
    const int* dst = ei + NE;

    char* ws = (char*)d_ws;
    size_t o = 0;
    auto alloc = [&](size_t bytes) { char* p = ws + o; o += (bytes + 255) & ~size_t(255); return p; };
    int*   cnt    = (int*)alloc(NN * 4);
    int*   rowptr = (int*)alloc((NN + 1) * 4);
    int*   bsum   = (int*)alloc(512 * 4);
    int*   gcur   = (int*)alloc(NB * 4);
    float* dinv   = (float*)alloc(NN * 4);
    int*   col    = (int*)alloc((size_t)NE * 4);
    float* xs     = (float*)alloc((size_t)NN * D0 * 4);  // 25.6 MB
    float* agg1x  = (float*)alloc((size_t)NN * D0 * 4);  // 25.6 MB
    float* y2     = (float*)alloc((size_t)NN * D2 * 4);  // 25.6 MB
    unsigned* packed = (unsigned*)agg1x;  // dead before k_gather1x writes agg
    // W-split buffers alias cnt (400 KB; dead after k_dinv). 4 x 16 KB = 64 KB.
    // Keeps workspace footprint identical to the verified baseline kernel.
    u16* W1h = (u16*)(cnt);
    u16* W1l = W1h + 8192;
    u16* W2h = W1l + 8192;
    u16* W2l = W2h + 8192;

    const int NBn = (NN + 255) / 256;
    const int NBe = (NE + 255) / 256;

    k_zero_cnt   <<<NBn, 256, 0, stream>>>(cnt);
    k_hist       <<<NBe, 256, 0, stream>>>(dst, cnt);
    k_scan_block <<<NBn, 256, 0, stream>>>(cnt, rowptr, bsum);
    k_scan_bsum  <<<1, 512, 0, stream>>>(bsum, gcur);
    k_scan_add   <<<NBn, 256, 0, stream>>>(rowptr, bsum);
    k_dinv       <<<NBn, 256, 0, stream>>>(cnt, dinv);
    k_splitW     <<<32, 256, 0, stream>>>(W1, W2, W1h, W1l, W2h, W2l);  // after k_dinv: cnt dead
    k_part       <<<(NE + TILE - 1) / TILE, 256, 0, stream>>>(src, dst, gcur, packed);
    k_fill2      <<<NB, 256, 0, stream>>>(bsum, rowptr, packed, col);
    k_prescale   <<<(NN * 16 + 255) / 256, 256, 0, stream>>>(x, dinv, xs);

    k_gather1x   <<<(NN * 64 + 255) / 256, 256, 0, stream>>>(rowptr, col, xs, dinv, agg1x);
    k_gemm12     <<<(NN + 63) / 64, 256, 0, stream>>>(agg1x, W1h, W1l, b1, W2h, W2l, dinv, y2);
    k_gather2_final<<<(NN * 64 + 255) / 256, 256, 0, stream>>>(rowptr, col, y2, dinv,
                                                               b2, Wfc, bfc, out);
}

// Round 3
// 286.341 us; speedup vs baseline: 1.3241x; 1.2098x over previous
//
#include <hip/hip_runtime.h>

// ProteinGCN: 2x GCNConv(+relu) + FC head. N=100k, E=1.6M, 64->128->64->1.
// Round 8: k_hist was top dispatch (65 us): 1.6M device-scope atomics over
// 100k counters, WRITE_SIZE 50MB (~31B write-back per atomic), VALU 0.4% --
// pure atomic-fabric latency. Replace the whole CSR build with a two-level
// scheme: k_bcount LDS-histograms the 391 dst-buckets (76k global atomics to
// 391 addrs), scan buckets, k_part partitions edges (unchanged), then
// k_bucket (one block per bucket) LDS-histograms the 256 local node ids from
// packed, derives dinv, scans to rowptr, and scatters col with LDS cursors.
// Replaces k_zero_cnt/k_hist/k_scan_block/k_scan_add/k_dinv/k_fill2.
// GEMMs stay split-bf16 MFMA (round 6/7): 3x mfma_f32_16x16x32_bf16 per fp32
// product; weights pre-split into B-fragment order; h1 packed (hi|lo<<16) in
// LDS stride 132; one barrier.

constexpr int NN = 100000;
constexpr int NE = 1600000;
constexpr int D0 = 64;   // input dim
constexpr int D1 = 128;  // hidden 1
constexpr int D2 = 64;   // hidden 2
constexpr int NB = (NN + 255) / 256;  // 391 buckets
constexpr int TILE = 8192;            // edges per k_part/k_bcount block
constexpr int H1STRIDE = 132;         // h1 LDS row stride (u32)

typedef unsigned short u16;
typedef unsigned int u32;
typedef __attribute__((ext_vector_type(8))) short short8;  // 8 bf16 (4 VGPR)
typedef __attribute__((ext_vector_type(4))) float f32x4;

// ---------------- CSR build ----------------

__global__ __launch_bounds__(256) void k_zero_b(int* __restrict__ g) {
    int i = blockIdx.x * 256 + threadIdx.x;
    if (i < 512) g[i] = 0;
}

// per-tile LDS histogram of dst-buckets -> global bucket counts
__global__ __launch_bounds__(256) void k_bcount(const int* __restrict__ dst,
                                                int* __restrict__ gbcnt) {
    __shared__ int cnt_s[NB];
    int tid = threadIdx.x;
    int e0 = blockIdx.x * TILE;
    int ecnt = NE - e0 < TILE ? NE - e0 : TILE;
    for (int i = tid; i < NB; i += 256) cnt_s[i] = 0;
    __syncthreads();
    for (int i = tid; i < ecnt; i += 256)
        atomicAdd(&cnt_s[dst[e0 + i] >> 8], 1);
    __syncthreads();
    for (int i = tid; i < NB; i += 256) {
        int c = cnt_s[i];
        if (c) atomicAdd(&gbcnt[i], c);
    }
}

// scan 391 bucket counts -> bucket bases (bsum, bsum[NB]=NE) + part cursors
__global__ __launch_bounds__(512) void k_scan_bsum(const int* __restrict__ gbcnt,
                                                   int* __restrict__ bsum,
                                                   int* __restrict__ gcur) {
    __shared__ int s[512];
    int tid = threadIdx.x;
    int v = (tid < NB) ? gbcnt[tid] : 0;
    s[tid] = v;
    __syncthreads();
#pragma unroll
    for (int off = 1; off < 512; off <<= 1) {
        int t = (tid >= off) ? s[tid - off] : 0;
        __syncthreads();
        s[tid] += t;
        __syncthreads();
    }
    int ex = s[tid] - v;  // exclusive scan
    if (tid <= NB) bsum[tid] = ex;   // bsum[NB] == NE
    if (tid < NB) gcur[tid] = ex;
}

// ---- partition edges into dst-buckets, packed (dl<<24)|src ----
__global__ __launch_bounds__(256) void k_part(const int* __restrict__ src,
                                              const int* __restrict__ dst,
                                              int* __restrict__ gcur,
                                              unsigned* __restrict__ packed) {
    __shared__ int cnt_s[NB];
    __shared__ int gbase_s[NB];
    __shared__ int cur_s[NB];
    int tid = threadIdx.x;
    int e0 = blockIdx.x * TILE;
    int ecnt = NE - e0 < TILE ? NE - e0 : TILE;
    for (int i = tid; i < NB; i += 256) cnt_s[i] = 0;
    __syncthreads();
    for (int i = tid; i < ecnt; i += 256)
        atomicAdd(&cnt_s[dst[e0 + i] >> 8], 1);
    __syncthreads();
    for (int i = tid; i < NB; i += 256) {
        int c = cnt_s[i];
        gbase_s[i] = c ? atomicAdd(&gcur[i], c) : 0;
        cur_s[i] = 0;
    }
    __syncthreads();
    for (int i = tid; i < ecnt; i += 256) {
        int d = dst[e0 + i];
        int s = src[e0 + i];
        int b = d >> 8;
        int slot = atomicAdd(&cur_s[b], 1);
        packed[gbase_s[b] + slot] = ((unsigned)(d & 255) << 24) | (unsigned)s;
    }
}

// ---- one block per bucket: node histogram -> dinv + rowptr, scatter col ----
__global__ __launch_bounds__(256) void k_bucket(const int* __restrict__ bsum,
                                                const unsigned* __restrict__ packed,
                                                int* __restrict__ rowptr,
                                                float* __restrict__ dinv,
                                                int* __restrict__ col) {
    __shared__ int hist[256];
    __shared__ int s[256];
    __shared__ int cur[256];
    int b = blockIdx.x;
    int tid = threadIdx.x;
    int e0 = bsum[b], e1 = bsum[b + 1];
    hist[tid] = 0;
    __syncthreads();
    for (int e = e0 + tid; e < e1; e += 256)
        atomicAdd(&hist[packed[e] >> 24], 1);
    __syncthreads();
    int v = hist[tid];
    int n = (b << 8) + tid;
    if (n < NN) dinv[n] = rsqrtf((float)(v + 1));
    // exclusive scan of per-node counts
    s[tid] = v;
    __syncthreads();
#pragma unroll
    for (int off = 1; off < 256; off <<= 1) {
        int t = (tid >= off) ? s[tid - off] : 0;
        __syncthreads();
        s[tid] += t;
        __syncthreads();
    }
    int base = e0 + s[tid] - v;
    if (n <= NN) rowptr[n] = base;   // n==NN (last bucket) lands on e1==NE
    cur[tid] = base;
    __syncthreads();
    for (int e = e0 + tid; e < e1; e += 256) {
        unsigned p = packed[e];
        int pos = atomicAdd(&cur[p >> 24], 1);
        col[pos] = (int)(p & 0xFFFFFFu);
    }
}

// ---------------- helpers ----------------

__device__ __forceinline__ float4 scale4(const float4& a, float s) {
    return float4{a.x * s, a.y * s, a.z * s, a.w * s};
}

__device__ __forceinline__ void add4(float4& a, const float4& b) {
    a.x += b.x; a.y += b.y; a.z += b.z; a.w += b.w;
}

__device__ __forceinline__ void xor_reduce4(float4& a, int mask) {
    a.x += __shfl_xor(a.x, mask, 64);
    a.y += __shfl_xor(a.y, mask, 64);
    a.z += __shfl_xor(a.z, mask, 64);
    a.w += __shfl_xor(a.w, mask, 64);
}

// bf16 RNE conversion + back
__device__ __forceinline__ u16 f2bf(float f) {
    u32 u = __float_as_uint(f);
    return (u16)((u + 0x7fffu + ((u >> 16) & 1u)) >> 16);
}
__device__ __forceinline__ float bf2f(u16 h) {
    return __uint_as_float(((u32)h) << 16);
}

// ---------------- prescale: xs = x * dinv ----------------
__global__ __launch_bounds__(256) void k_prescale(const float* __restrict__ x,
                                                  const float* __restrict__ dinv,
                                                  float* __restrict__ xs) {
    int i = blockIdx.x * 256 + threadIdx.x;  // float4 index
    if (i >= NN * 16) return;
    float di = dinv[i >> 4];
    ((float4*)xs)[i] = scale4(((const float4*)x)[i], di);
}

// ---------------- layer-1 gather on prescaled xs ----------------
// agg[d] = dinv_d * ( xs[d] + sum_{s in in(d)} xs[s] )
__global__ __launch_bounds__(256) void k_gather1x(const int* __restrict__ rowptr,
                                                  const int* __restrict__ col,
                                                  const float* __restrict__ xs,
                                                  const float* __restrict__ dinv,
                                                  float* __restrict__ agg) {
    int wave = (blockIdx.x * 256 + threadIdx.x) >> 6;
    int lane = threadIdx.x & 63;
    if (wave >= NN) return;
    int f4 = lane & 15;   // float4 index within 64-float row
    int es = lane >> 4;   // edge sublane 0..3
    int r0 = rowptr[wave], r1 = rowptr[wave + 1];
    const float4* xs4 = (const float4*)xs;
    float4 acc{0, 0, 0, 0};
    if (es == 0) acc = xs4[(size_t)wave * 16 + f4];  // self loop (once)
    int e = r0 + es;
    for (; e + 4 < r1; e += 8) {
        int s0 = col[e];
        int s1 = col[e + 4];
        float4 v0 = xs4[(size_t)s0 * 16 + f4];
        float4 v1 = xs4[(size_t)s1 * 16 + f4];
        add4(acc, v0);
        add4(acc, v1);
    }
    for (; e < r1; e += 4) {
        float4 v = xs4[(size_t)col[e] * 16 + f4];
        add4(acc, v);
    }
    xor_reduce4(acc, 16);
    xor_reduce4(acc, 32);
    if (es == 0)
        ((float4*)agg)[(size_t)wave * 16 + f4] = scale4(acc, dinv[wave]);
}

// ---------------- weight pre-split into MFMA B-fragment order ----------------
// B-fragment (16x16x32 bf16): lane l holds B[k][col], col=l&15, k=(l>>4)*8+j.
// W1 frags: [(s*8+t)*64 + l]*8 + j  (s: k-step 0..1, t: n-tile 0..7)
// W2 frags: [(s*4+t)*64 + l]*8 + j  (s: k-step 0..3, t: n-tile 0..3)
__global__ __launch_bounds__(256) void k_splitW(const float* __restrict__ W1,
                                                const float* __restrict__ W2,
                                                u16* __restrict__ W1h, u16* __restrict__ W1l,
                                                u16* __restrict__ W2h, u16* __restrict__ W2l) {
    int i = blockIdx.x * 256 + threadIdx.x;  // 0..8191
    if (i >= 8192) return;
    int j = i & 7;
    int l = (i >> 3) & 63;
    int ts = i >> 9;                 // 0..15
    int kf = ((l >> 4) << 3) + j;    // k within 32-step
    int cl = l & 15;
    {   // W1 [64][128]: ts = s*8 + t
        int s = ts >> 3, t = ts & 7;
        float w = W1[(s * 32 + kf) * D1 + t * 16 + cl];
        u16 h = f2bf(w);
        W1h[i] = h;
        W1l[i] = f2bf(w - bf2f(h));
    }
    {   // W2 [128][64]: ts = s*4 + t
        int s = ts >> 2, t = ts & 3;
        float w = W2[(s * 32 + kf) * D2 + t * 16 + cl];
        u16 h = f2bf(w);
        W2h[i] = h;
        W2l[i] = f2bf(w - bf2f(h));
    }
}

// ---------------- fused GEMM1 + GEMM2 via split-bf16 MFMA ----------------
// h1 = relu(agg @ W1 + b1)   (64 -> 128, packed hi/lo bf16 in LDS)
// y2 = (h1 @ W2) * dinv      (128 -> 64)
// Block: 64 nodes, 4 waves; wave w owns node rows w*16..w*16+15.
__global__ __launch_bounds__(256) void k_gemm12(const float* __restrict__ agg,
                                                const u16* __restrict__ W1h,
                                                const u16* __restrict__ W1l,
                                                const float* __restrict__ b1,
                                                const u16* __restrict__ W2h,
                                                const u16* __restrict__ W2l,
                                                const float* __restrict__ dinv,
                                                float* __restrict__ y2) {
    __shared__ u32 h1s[64 * H1STRIDE];  // packed (hi | lo<<16), 33.8 KB
    int tid = threadIdx.x;
    int l = tid & 63;
    int wv = tid >> 6;
    int n_base = blockIdx.x * 64;
    int row_a = l & 15;           // A-operand row within 16-tile
    int kg = (l >> 4) << 3;       // k offset within 32-step: 0,8,16,24
    int crow = (l >> 4) * 4;      // C/D row base: (lane>>4)*4

    // ---- phase A: h1 = relu(agg @ W1 + b1) ----
    short8 Ah[2], Al[2];
#pragma unroll
    for (int s = 0; s < 2; ++s) {
        int an = n_base + wv * 16 + row_a;
        if (an >= NN) an = NN - 1;  // clamp: dup rows, outputs discarded
        const float* ap = agg + (size_t)an * D0 + s * 32 + kg;
        f32x4 v0 = *(const f32x4*)ap;
        f32x4 v1 = *(const f32x4*)(ap + 4);
#pragma unroll
        for (int j = 0; j < 4; ++j) {
            u16 h0 = f2bf(v0[j]);
            Ah[s][j] = (short)h0;
            Al[s][j] = (short)f2bf(v0[j] - bf2f(h0));
            u16 h1b = f2bf(v1[j]);
            Ah[s][j + 4] = (short)h1b;
            Al[s][j + 4] = (short)f2bf(v1[j] - bf2f(h1b));
        }
    }
#pragma unroll
    for (int t = 0; t < 8; ++t) {
        f32x4 acc = {0.f, 0.f, 0.f, 0.f};
#pragma unroll
        for (int s = 0; s < 2; ++s) {
            short8 Bh = *(const short8*)(W1h + ((size_t)(s * 8 + t) * 64 + l) * 8);
            short8 Bl = *(const short8*)(W1l + ((size_t)(s * 8 + t) * 64 + l) * 8);
            acc = __builtin_amdgcn_mfma_f32_16x16x32_bf16(Ah[s], Bh, acc, 0, 0, 0);
            acc = __builtin_amdgcn_mfma_f32_16x16x32_bf16(Ah[s], Bl, acc, 0, 0, 0);
            acc = __builtin_amdgcn_mfma_f32_16x16x32_bf16(Al[s], Bh, acc, 0, 0, 0);
        }
        // epilogue: +b1, relu, split-pack to LDS (C/D: row=(l>>4)*4+r, col=l&15)
        float bb = b1[t * 16 + (l & 15)];
        int kcol = t * 16 + (l & 15);  // h1 feature index = GEMM2 k
#pragma unroll
        for (int r = 0; r < 4; ++r) {
            int row = wv * 16 + crow + r;  // node row in 64-tile
            float v = fmaxf(acc[r] + bb, 0.f);
            u16 h = f2bf(v);
            u16 lo = f2bf(v - bf2f(h));
            h1s[row * H1STRIDE + kcol] = (u32)h | ((u32)lo << 16);
        }
    }
    __syncthreads();

    // ---- phase B: y2 = (h1 @ W2) * dinv ----
    short8 A2h[4], A2l[4];
#pragma unroll
    for (int s = 0; s < 4; ++s) {
        int row = wv * 16 + row_a;
        const u32* hp = &h1s[row * H1STRIDE + s * 32 + kg];
        uint4 p0 = *(const uint4*)hp;
        uint4 p1 = *(const uint4*)(hp + 4);
        u32 pv[8] = {p0.x, p0.y, p0.z, p0.w, p1.x, p1.y, p1.z, p1.w};
#pragma unroll
        for (int j = 0; j < 8; ++j) {
            A2h[s][j] = (short)(pv[j] & 0xffffu);
            A2l[s][j] = (short)(pv[j] >> 16);
        }
    }
#pragma unroll
    for (int t = 0; t < 4; ++t) {
        f32x4 acc = {0.f, 0.f, 0.f, 0.f};
#pragma unroll
        for (int s = 0; s < 4; ++s) {
            short8 Bh = *(const short8*)(W2h + ((size_t)(s * 4 + t) * 64 + l) * 8);
            short8 Bl = *(const short8*)(W2l + ((size_t)(s * 4 + t) * 64 + l) * 8);
            acc = __builtin_amdgcn_mfma_f32_16x16x32_bf16(A2h[s], Bh, acc, 0, 0, 0);
            acc = __builtin_amdgcn_mfma_f32_16x16x32_bf16(A2h[s], Bl, acc, 0, 0, 0);
            acc = __builtin_amdgcn_mfma_f32_16x16x32_bf16(A2l[s], Bh, acc, 0, 0, 0);
        }
#pragma unroll
        for (int r = 0; r < 4; ++r) {
            int n = n_base + wv * 16 + crow + r;
            if (n < NN) y2[(size_t)n * D2 + t * 16 + (l & 15)] = acc[r] * dinv[n];
        }
    }
}

// ---------------- layer-2 gather fused with FC head ----------------
// acc = y2[d] + sum y2[s]; out[d] = relu(acc*dinv_d + b2) . Wfc + bfc
__global__ __launch_bounds__(256) void k_gather2_final(const int* __restrict__ rowptr,
                                                       const int* __restrict__ col,
                                                       const float* __restrict__ y2,
                                                       const float* __restrict__ dinv,
                                                       const float* __restrict__ b2,
                                                       const float* __restrict__ Wfc,
                                                       const float* __restrict__ bfc,
                                                       float* __restrict__ out) {
    int wave = (blockIdx.x * 256 + threadIdx.x) >> 6;
    int lane = threadIdx.x & 63;
    if (wave >= NN) return;
    int f4 = lane & 15;
    int es = lane >> 4;
    int r0 = rowptr[wave], r1 = rowptr[wave + 1];
    const float4* y24 = (const float4*)y2;
    float4 acc{0, 0, 0, 0};
    if (es == 0) acc = y24[(size_t)wave * 16 + f4];  // self loop (once)
    int e = r0 + es;
    for (; e + 4 < r1; e += 8) {
        int s0 = col[e];
        int s1 = col[e + 4];
        float4 v0 = y24[(size_t)s0 * 16 + f4];
        float4 v1 = y24[(size_t)s1 * 16 + f4];
        add4(acc, v0);
        add4(acc, v1);
    }
    for (; e < r1; e += 4) {
        float4 v = y24[(size_t)col[e] * 16 + f4];
        add4(acc, v);
    }
    xor_reduce4(acc, 16);
    xor_reduce4(acc, 32);
    // every lane now holds the feature-group sum for its f4 (4 copies)
    float di = dinv[wave];
    float4 b = ((const float4*)b2)[f4];
    float4 w = ((const float4*)Wfc)[f4];
    float p = fmaxf(fmaf(acc.x, di, b.x), 0.f) * w.x
            + fmaxf(fmaf(acc.y, di, b.y), 0.f) * w.y
            + fmaxf(fmaf(acc.z, di, b.z), 0.f) * w.z
            + fmaxf(fmaf(acc.w, di, b.w), 0.f) * w.w;
    // sum the 16 f4 groups (each 16-lane block holds all 16 f4 values)
    p += __shfl_xor(p, 1, 64);
    p += __shfl_xor(p, 2, 64);
    p += __shfl_xor(p, 4, 64);
    p += __shfl_xor(p, 8, 64);
    if (lane == 0) out[wave] = p + bfc[0];
}

extern "C" void kernel_launch(void* const* d_in, const int* in_sizes, int n_in,
                              void* d_out, int out_size, void* d_ws, size_t ws_size,
                              hipStream_t stream) {
    const float* x   = (const float*)d_in[0];
    const int*   ei  = (const int*)d_in[1];   // [2, E] int
    const float* W1  = (const float*)d_in[2];
    const float* b1  = (const float*)d_in[3];
    const float* W2  = (const float*)d_in[4];
    const float* b2  = (const float*)d_in[5];
    const float* Wfc = (const float*)d_in[6];
    const float* bfc = (const float*)d_in[7];
    float* out = (float*)d_out;

    const int* src = ei;
    const int* dst = ei + NE;

    char* ws = (char*)d_ws;
    size_t o = 0;
    auto alloc = [&](size_t bytes) { char* p = ws + o; o += (bytes + 255) & ~size_t(255); return p; };
    int*   scratch = (int*)alloc(NN * 4);      // 400 KB: gbcnt + W-split buffers
    int*   rowptr = (int*)alloc((NN + 1) * 4);
    int*   bsum   = (int*)alloc(512 * 4);
    int*   gcur   = (int*)alloc(NB * 4);
    float* dinv   = (float*)alloc(NN * 4);
    int*   col    = (int*)alloc((size_t)NE * 4);
    float* xs     = (float*)alloc((size_t)NN * D0 * 4);  // 25.6 MB
    float* agg1x  = (float*)alloc((size_t)NN * D0 * 4);  // 25.6 MB
    float* y2     = (float*)alloc((size_t)NN * D2 * 4);  // 25.6 MB
    unsigned* packed = (unsigned*)agg1x;  // dead before k_gather1x writes agg
    // carve scratch: bucket counts (512 ints) then the 4 x 16 KB weight splits
    int* gbcnt = scratch;
    u16* W1h = (u16*)(scratch + 512);
    u16* W1l = W1h + 8192;
    u16* W2h = W1l + 8192;
    u16* W2l = W2h + 8192;

    const int NT = (NE + TILE - 1) / TILE;  // 196 tiles

    k_zero_b    <<<2, 256, 0, stream>>>(gbcnt);
    k_splitW    <<<32, 256, 0, stream>>>(W1, W2, W1h, W1l, W2h, W2l);
    k_bcount    <<<NT, 256, 0, stream>>>(dst, gbcnt);
    k_scan_bsum <<<1, 512, 0, stream>>>(gbcnt, bsum, gcur);
    k_part      <<<NT, 256, 0, stream>>>(src, dst, gcur, packed);
    k_bucket    <<<NB, 256, 0, stream>>>(bsum, packed, rowptr, dinv, col);
    k_prescale  <<<(NN * 16 + 255) / 256, 256, 0, stream>>>(x, dinv, xs);

    k_gather1x  <<<(NN * 64 + 255) / 256, 256, 0, stream>>>(rowptr, col, xs, dinv, agg1x);
    k_gemm12    <<<(NN + 63) / 64, 256, 0, stream>>>(agg1x, W1h, W1l, b1, W2h, W2l, dinv, y2);
    k_gather2_final<<<(NN * 64 + 255) / 256, 256, 0, stream>>>(rowptr, col, y2, dinv,
                                                               b2, Wfc, bfc, out);
}

// Round 4
// 261.570 us; speedup vs baseline: 1.4495x; 1.0947x over previous
//
#include <hip/hip_runtime.h>

// ProteinGCN: 2x GCNConv(+relu) + FC head. N=100k, E=1.6M, 64->128->64->1.
// Round 9: k_gather1x top dispatch (62 us, FETCH 190MB, 3.5 TB/s): random
// gather of 256B fp32 rows, traffic-bound past L2 (random graph -> no
// locality lever). Halve bytes/edge: store gathered operands (xs, y2) as
// fp16 rows (128B), accumulate fp32. Adds ~4.9e-4 rel rounding per gathered
// element (absmax headroom exists; fallback = fp16 on y2 only).
// CSR build: two-level bucket scheme (round 8). GEMMs: split-bf16 MFMA
// (rounds 6/7), y2 epilogue now emits fp16.

constexpr int NN = 100000;
constexpr int NE = 1600000;
constexpr int D0 = 64;   // input dim
constexpr int D1 = 128;  // hidden 1
constexpr int D2 = 64;   // hidden 2
constexpr int NB = (NN + 255) / 256;  // 391 buckets
constexpr int TILE = 8192;            // edges per k_part/k_bcount block
constexpr int H1STRIDE = 132;         // h1 LDS row stride (u32)

typedef unsigned short u16;
typedef unsigned int u32;
typedef __attribute__((ext_vector_type(8))) short short8;  // 8 bf16 (4 VGPR)
typedef __attribute__((ext_vector_type(4))) float f32x4;
typedef _Float16 h4 __attribute__((ext_vector_type(4)));   // 4 fp16 = 8 B

// ---------------- CSR build ----------------

__global__ __launch_bounds__(256) void k_zero_b(int* __restrict__ g) {
    int i = blockIdx.x * 256 + threadIdx.x;
    if (i < 512) g[i] = 0;
}

// per-tile LDS histogram of dst-buckets -> global bucket counts
__global__ __launch_bounds__(256) void k_bcount(const int* __restrict__ dst,
                                                int* __restrict__ gbcnt) {
    __shared__ int cnt_s[NB];
    int tid = threadIdx.x;
    int e0 = blockIdx.x * TILE;
    int ecnt = NE - e0 < TILE ? NE - e0 : TILE;
    for (int i = tid; i < NB; i += 256) cnt_s[i] = 0;
    __syncthreads();
    for (int i = tid; i < ecnt; i += 256)
        atomicAdd(&cnt_s[dst[e0 + i] >> 8], 1);
    __syncthreads();
    for (int i = tid; i < NB; i += 256) {
        int c = cnt_s[i];
        if (c) atomicAdd(&gbcnt[i], c);
    }
}

// scan 391 bucket counts -> bucket bases (bsum, bsum[NB]=NE) + part cursors
__global__ __launch_bounds__(512) void k_scan_bsum(const int* __restrict__ gbcnt,
                                                   int* __restrict__ bsum,
                                                   int* __restrict__ gcur) {
    __shared__ int s[512];
    int tid = threadIdx.x;
    int v = (tid < NB) ? gbcnt[tid] : 0;
    s[tid] = v;
    __syncthreads();
#pragma unroll
    for (int off = 1; off < 512; off <<= 1) {
        int t = (tid >= off) ? s[tid - off] : 0;
        __syncthreads();
        s[tid] += t;
        __syncthreads();
    }
    int ex = s[tid] - v;  // exclusive scan
    if (tid <= NB) bsum[tid] = ex;   // bsum[NB] == NE
    if (tid < NB) gcur[tid] = ex;
}

// ---- partition edges into dst-buckets, packed (dl<<24)|src ----
__global__ __launch_bounds__(256) void k_part(const int* __restrict__ src,
                                              const int* __restrict__ dst,
                                              int* __restrict__ gcur,
                                              unsigned* __restrict__ packed) {
    __shared__ int cnt_s[NB];
    __shared__ int gbase_s[NB];
    __shared__ int cur_s[NB];
    int tid = threadIdx.x;
    int e0 = blockIdx.x * TILE;
    int ecnt = NE - e0 < TILE ? NE - e0 : TILE;
    for (int i = tid; i < NB; i += 256) cnt_s[i] = 0;
    __syncthreads();
    for (int i = tid; i < ecnt; i += 256)
        atomicAdd(&cnt_s[dst[e0 + i] >> 8], 1);
    __syncthreads();
    for (int i = tid; i < NB; i += 256) {
        int c = cnt_s[i];
        gbase_s[i] = c ? atomicAdd(&gcur[i], c) : 0;
        cur_s[i] = 0;
    }
    __syncthreads();
    for (int i = tid; i < ecnt; i += 256) {
        int d = dst[e0 + i];
        int s = src[e0 + i];
        int b = d >> 8;
        int slot = atomicAdd(&cur_s[b], 1);
        packed[gbase_s[b] + slot] = ((unsigned)(d & 255) << 24) | (unsigned)s;
    }
}

// ---- one block per bucket: node histogram -> dinv + rowptr, scatter col ----
__global__ __launch_bounds__(256) void k_bucket(const int* __restrict__ bsum,
                                                const unsigned* __restrict__ packed,
                                                int* __restrict__ rowptr,
                                                float* __restrict__ dinv,
                                                int* __restrict__ col) {
    __shared__ int hist[256];
    __shared__ int s[256];
    __shared__ int cur[256];
    int b = blockIdx.x;
    int tid = threadIdx.x;
    int e0 = bsum[b], e1 = bsum[b + 1];
    hist[tid] = 0;
    __syncthreads();
    for (int e = e0 + tid; e < e1; e += 256)
        atomicAdd(&hist[packed[e] >> 24], 1);
    __syncthreads();
    int v = hist[tid];
    int n = (b << 8) + tid;
    if (n < NN) dinv[n] = rsqrtf((float)(v + 1));
    // exclusive scan of per-node counts
    s[tid] = v;
    __syncthreads();
#pragma unroll
    for (int off = 1; off < 256; off <<= 1) {
        int t = (tid >= off) ? s[tid - off] : 0;
        __syncthreads();
        s[tid] += t;
        __syncthreads();
    }
    int base = e0 + s[tid] - v;
    if (n <= NN) rowptr[n] = base;   // n==NN (last bucket) lands on e1==NE
    cur[tid] = base;
    __syncthreads();
    for (int e = e0 + tid; e < e1; e += 256) {
        unsigned p = packed[e];
        int pos = atomicAdd(&cur[p >> 24], 1);
        col[pos] = (int)(p & 0xFFFFFFu);
    }
}

// ---------------- helpers ----------------

__device__ __forceinline__ float4 scale4(const float4& a, float s) {
    return float4{a.x * s, a.y * s, a.z * s, a.w * s};
}

__device__ __forceinline__ void addh4(float4& a, uint2 u) {
    h4 h = *(h4*)&u;
    a.x += (float)h[0]; a.y += (float)h[1]; a.z += (float)h[2]; a.w += (float)h[3];
}

__device__ __forceinline__ uint2 packh4(const float4& v) {
    h4 h;
    h[0] = (_Float16)v.x; h[1] = (_Float16)v.y;
    h[2] = (_Float16)v.z; h[3] = (_Float16)v.w;
    return *(uint2*)&h;
}

__device__ __forceinline__ void xor_reduce4(float4& a, int mask) {
    a.x += __shfl_xor(a.x, mask, 64);
    a.y += __shfl_xor(a.y, mask, 64);
    a.z += __shfl_xor(a.z, mask, 64);
    a.w += __shfl_xor(a.w, mask, 64);
}

// bf16 RNE conversion + back
__device__ __forceinline__ u16 f2bf(float f) {
    u32 u = __float_as_uint(f);
    return (u16)((u + 0x7fffu + ((u >> 16) & 1u)) >> 16);
}
__device__ __forceinline__ float bf2f(u16 h) {
    return __uint_as_float(((u32)h) << 16);
}

// ---------------- prescale: xs = fp16(x * dinv) ----------------
__global__ __launch_bounds__(256) void k_prescale(const float* __restrict__ x,
                                                  const float* __restrict__ dinv,
                                                  u16* __restrict__ xs) {
    int i = blockIdx.x * 256 + threadIdx.x;  // float4 / uint2 index
    if (i >= NN * 16) return;
    float di = dinv[i >> 4];
    ((uint2*)xs)[i] = packh4(scale4(((const float4*)x)[i], di));
}

// ---------------- layer-1 gather on prescaled fp16 xs ----------------
// agg[d] = dinv_d * ( xs[d] + sum_{s in in(d)} xs[s] )  (fp32 accum)
__global__ __launch_bounds__(256) void k_gather1x(const int* __restrict__ rowptr,
                                                  const int* __restrict__ col,
                                                  const u16* __restrict__ xs,
                                                  const float* __restrict__ dinv,
                                                  float* __restrict__ agg) {
    int wave = (blockIdx.x * 256 + threadIdx.x) >> 6;
    int lane = threadIdx.x & 63;
    if (wave >= NN) return;
    int f4 = lane & 15;   // uint2 (4-half) index within 64-half row
    int es = lane >> 4;   // edge sublane 0..3
    int r0 = rowptr[wave], r1 = rowptr[wave + 1];
    const uint2* xs4 = (const uint2*)xs;
    float4 acc{0, 0, 0, 0};
    if (es == 0) addh4(acc, xs4[(size_t)wave * 16 + f4]);  // self loop (once)
    int e = r0 + es;
    for (; e + 4 < r1; e += 8) {
        int s0 = col[e];
        int s1 = col[e + 4];
        uint2 v0 = xs4[(size_t)s0 * 16 + f4];
        uint2 v1 = xs4[(size_t)s1 * 16 + f4];
        addh4(acc, v0);
        addh4(acc, v1);
    }
    for (; e < r1; e += 4) {
        uint2 v = xs4[(size_t)col[e] * 16 + f4];
        addh4(acc, v);
    }
    xor_reduce4(acc, 16);
    xor_reduce4(acc, 32);
    if (es == 0)
        ((float4*)agg)[(size_t)wave * 16 + f4] = scale4(acc, dinv[wave]);
}

// ---------------- weight pre-split into MFMA B-fragment order ----------------
// B-fragment (16x16x32 bf16): lane l holds B[k][col], col=l&15, k=(l>>4)*8+j.
// W1 frags: [(s*8+t)*64 + l]*8 + j  (s: k-step 0..1, t: n-tile 0..7)
// W2 frags: [(s*4+t)*64 + l]*8 + j  (s: k-step 0..3, t: n-tile 0..3)
__global__ __launch_bounds__(256) void k_splitW(const float* __restrict__ W1,
                                                const float* __restrict__ W2,
                                                u16* __restrict__ W1h, u16* __restrict__ W1l,
                                                u16* __restrict__ W2h, u16* __restrict__ W2l) {
    int i = blockIdx.x * 256 + threadIdx.x;  // 0..8191
    if (i >= 8192) return;
    int j = i & 7;
    int l = (i >> 3) & 63;
    int ts = i >> 9;                 // 0..15
    int kf = ((l >> 4) << 3) + j;    // k within 32-step
    int cl = l & 15;
    {   // W1 [64][128]: ts = s*8 + t
        int s = ts >> 3, t = ts & 7;
        float w = W1[(s * 32 + kf) * D1 + t * 16 + cl];
        u16 h = f2bf(w);
        W1h[i] = h;
        W1l[i] = f2bf(w - bf2f(h));
    }
    {   // W2 [128][64]: ts = s*4 + t
        int s = ts >> 2, t = ts & 3;
        float w = W2[(s * 32 + kf) * D2 + t * 16 + cl];
        u16 h = f2bf(w);
        W2h[i] = h;
        W2l[i] = f2bf(w - bf2f(h));
    }
}

// ---------------- fused GEMM1 + GEMM2 via split-bf16 MFMA ----------------
// h1 = relu(agg @ W1 + b1)   (64 -> 128, packed hi/lo bf16 in LDS)
// y2 = fp16((h1 @ W2) * dinv)  (128 -> 64)
// Block: 64 nodes, 4 waves; wave w owns node rows w*16..w*16+15.
__global__ __launch_bounds__(256) void k_gemm12(const float* __restrict__ agg,
                                                const u16* __restrict__ W1h,
                                                const u16* __restrict__ W1l,
                                                const float* __restrict__ b1,
                                                const u16* __restrict__ W2h,
                                                const u16* __restrict__ W2l,
                                                const float* __restrict__ dinv,
                                                u16* __restrict__ y2) {
    __shared__ u32 h1s[64 * H1STRIDE];  // packed (hi | lo<<16), 33.8 KB
    int tid = threadIdx.x;
    int l = tid & 63;
    int wv = tid >> 6;
    int n_base = blockIdx.x * 64;
    int row_a = l & 15;           // A-operand row within 16-tile
    int kg = (l >> 4) << 3;       // k offset within 32-step: 0,8,16,24
    int crow = (l >> 4) * 4;      // C/D row base: (lane>>4)*4

    // ---- phase A: h1 = relu(agg @ W1 + b1) ----
    short8 Ah[2], Al[2];
#pragma unroll
    for (int s = 0; s < 2; ++s) {
        int an = n_base + wv * 16 + row_a;
        if (an >= NN) an = NN - 1;  // clamp: dup rows, outputs discarded
        const float* ap = agg + (size_t)an * D0 + s * 32 + kg;
        f32x4 v0 = *(const f32x4*)ap;
        f32x4 v1 = *(const f32x4*)(ap + 4);
#pragma unroll
        for (int j = 0; j < 4; ++j) {
            u16 h0 = f2bf(v0[j]);
            Ah[s][j] = (short)h0;
            Al[s][j] = (short)f2bf(v0[j] - bf2f(h0));
            u16 h1b = f2bf(v1[j]);
            Ah[s][j + 4] = (short)h1b;
            Al[s][j + 4] = (short)f2bf(v1[j] - bf2f(h1b));
        }
    }
#pragma unroll
    for (int t = 0; t < 8; ++t) {
        f32x4 acc = {0.f, 0.f, 0.f, 0.f};
#pragma unroll
        for (int s = 0; s < 2; ++s) {
            short8 Bh = *(const short8*)(W1h + ((size_t)(s * 8 + t) * 64 + l) * 8);
            short8 Bl = *(const short8*)(W1l + ((size_t)(s * 8 + t) * 64 + l) * 8);
            acc = __builtin_amdgcn_mfma_f32_16x16x32_bf16(Ah[s], Bh, acc, 0, 0, 0);
            acc = __builtin_amdgcn_mfma_f32_16x16x32_bf16(Ah[s], Bl, acc, 0, 0, 0);
            acc = __builtin_amdgcn_mfma_f32_16x16x32_bf16(Al[s], Bh, acc, 0, 0, 0);
        }
        // epilogue: +b1, relu, split-pack to LDS (C/D: row=(l>>4)*4+r, col=l&15)
        float bb = b1[t * 16 + (l & 15)];
        int kcol = t * 16 + (l & 15);  // h1 feature index = GEMM2 k
#pragma unroll
        for (int r = 0; r < 4; ++r) {
            int row = wv * 16 + crow + r;  // node row in 64-tile
            float v = fmaxf(acc[r] + bb, 0.f);
            u16 h = f2bf(v);
            u16 lo = f2bf(v - bf2f(h));
            h1s[row * H1STRIDE + kcol] = (u32)h | ((u32)lo << 16);
        }
    }
    __syncthreads();

    // ---- phase B: y2 = fp16((h1 @ W2) * dinv) ----
    short8 A2h[4], A2l[4];
#pragma unroll
    for (int s = 0; s < 4; ++s) {
        int row = wv * 16 + row_a;
        const u32* hp = &h1s[row * H1STRIDE + s * 32 + kg];
        uint4 p0 = *(const uint4*)hp;
        uint4 p1 = *(const uint4*)(hp + 4);
        u32 pv[8] = {p0.x, p0.y, p0.z, p0.w, p1.x, p1.y, p1.z, p1.w};
#pragma unroll
        for (int j = 0; j < 8; ++j) {
            A2h[s][j] = (short)(pv[j] & 0xffffu);
            A2l[s][j] = (short)(pv[j] >> 16);
        }
    }
#pragma unroll
    for (int t = 0; t < 4; ++t) {
        f32x4 acc = {0.f, 0.f, 0.f, 0.f};
#pragma unroll
        for (int s = 0; s < 4; ++s) {
            short8 Bh = *(const short8*)(W2h + ((size_t)(s * 4 + t) * 64 + l) * 8);
            short8 Bl = *(const short8*)(W2l + ((size_t)(s * 4 + t) * 64 + l) * 8);
            acc = __builtin_amdgcn_mfma_f32_16x16x32_bf16(A2h[s], Bh, acc, 0, 0, 0);
            acc = __builtin_amdgcn_mfma_f32_16x16x32_bf16(A2h[s], Bl, acc, 0, 0, 0);
            acc = __builtin_amdgcn_mfma_f32_16x16x32_bf16(A2l[s], Bh, acc, 0, 0, 0);
        }
#pragma unroll
        for (int r = 0; r < 4; ++r) {
            int n = n_base + wv * 16 + crow + r;
            if (n < NN) {
                _Float16 hf = (_Float16)(acc[r] * dinv[n]);
                y2[(size_t)n * D2 + t * 16 + (l & 15)] = *(u16*)&hf;
            }
        }
    }
}

// ---------------- layer-2 gather fused with FC head ----------------
// acc = y2[d] + sum y2[s]; out[d] = relu(acc*dinv_d + b2) . Wfc + bfc
__global__ __launch_bounds__(256) void k_gather2_final(const int* __restrict__ rowptr,
                                                       const int* __restrict__ col,
                                                       const u16* __restrict__ y2,
                                                       const float* __restrict__ dinv,
                                                       const float* __restrict__ b2,
                                                       const float* __restrict__ Wfc,
                                                       const float* __restrict__ bfc,
                                                       float* __restrict__ out) {
    int wave = (blockIdx.x * 256 + threadIdx.x) >> 6;
    int lane = threadIdx.x & 63;
    if (wave >= NN) return;
    int f4 = lane & 15;
    int es = lane >> 4;
    int r0 = rowptr[wave], r1 = rowptr[wave + 1];
    const uint2* y24 = (const uint2*)y2;
    float4 acc{0, 0, 0, 0};
    if (es == 0) addh4(acc, y24[(size_t)wave * 16 + f4]);  // self loop (once)
    int e = r0 + es;
    for (; e + 4 < r1; e += 8) {
        int s0 = col[e];
        int s1 = col[e + 4];
        uint2 v0 = y24[(size_t)s0 * 16 + f4];
        uint2 v1 = y24[(size_t)s1 * 16 + f4];
        addh4(acc, v0);
        addh4(acc, v1);
    }
    for (; e < r1; e += 4) {
        uint2 v = y24[(size_t)col[e] * 16 + f4];
        addh4(acc, v);
    }
    xor_reduce4(acc, 16);
    xor_reduce4(acc, 32);
    // every lane now holds the feature-group sum for its f4 (4 copies)
    float di = dinv[wave];
    float4 b = ((const float4*)b2)[f4];
    float4 w = ((const float4*)Wfc)[f4];
    float p = fmaxf(fmaf(acc.x, di, b.x), 0.f) * w.x
            + fmaxf(fmaf(acc.y, di, b.y), 0.f) * w.y
            + fmaxf(fmaf(acc.z, di, b.z), 0.f) * w.z
            + fmaxf(fmaf(acc.w, di, b.w), 0.f) * w.w;
    // sum the 16 f4 groups (each 16-lane block holds all 16 f4 values)
    p += __shfl_xor(p, 1, 64);
    p += __shfl_xor(p, 2, 64);
    p += __shfl_xor(p, 4, 64);
    p += __shfl_xor(p, 8, 64);
    if (lane == 0) out[wave] = p + bfc[0];
}

extern "C" void kernel_launch(void* const* d_in, const int* in_sizes, int n_in,
                              void* d_out, int out_size, void* d_ws, size_t ws_size,
                              hipStream_t stream) {
    const float* x   = (const float*)d_in[0];
    const int*   ei  = (const int*)d_in[1];   // [2, E] int
    const float* W1  = (const float*)d_in[2];
    const float* b1  = (const float*)d_in[3];
    const float* W2  = (const float*)d_in[4];
    const float* b2  = (const float*)d_in[5];
    const float* Wfc = (const float*)d_in[6];
    const float* bfc = (const float*)d_in[7];
    float* out = (float*)d_out;

    const int* src = ei;
    const int* dst = ei + NE;

    char* ws = (char*)d_ws;
    size_t o = 0;
    auto alloc = [&](size_t bytes) { char* p = ws + o; o += (bytes + 255) & ~size_t(255); return p; };
    int*   scratch = (int*)alloc(NN * 4);      // 400 KB: gbcnt + W-split buffers
    int*   rowptr = (int*)alloc((NN + 1) * 4);
    int*   bsum   = (int*)alloc(512 * 4);
    int*   gcur   = (int*)alloc(NB * 4);
    float* dinv   = (float*)alloc(NN * 4);
    int*   col    = (int*)alloc((size_t)NE * 4);
    u16*   xs     = (u16*)alloc((size_t)NN * D0 * 2);    // 12.8 MB fp16
    float* agg1x  = (float*)alloc((size_t)NN * D0 * 4);  // 25.6 MB fp32
    u16*   y2     = (u16*)alloc((size_t)NN * D2 * 2);    // 12.8 MB fp16
    unsigned* packed = (unsigned*)agg1x;  // dead before k_gather1x writes agg
    // carve scratch: bucket counts (512 ints) then the 4 x 16 KB weight splits
    int* gbcnt = scratch;
    u16* W1h = (u16*)(scratch + 512);
    u16* W1l = W1h + 8192;
    u16* W2h = W1l + 8192;
    u16* W2l = W2h + 8192;

    const int NT = (NE + TILE - 1) / TILE;  // 196 tiles

    k_zero_b    <<<2, 256, 0, stream>>>(gbcnt);
    k_splitW    <<<32, 256, 0, stream>>>(W1, W2, W1h, W1l, W2h, W2l);
    k_bcount    <<<NT, 256, 0, stream>>>(dst, gbcnt);
    k_scan_bsum <<<1, 512, 0, stream>>>(gbcnt, bsum, gcur);
    k_part      <<<NT, 256, 0, stream>>>(src, dst, gcur, packed);
    k_bucket    <<<NB, 256, 0, stream>>>(bsum, packed, rowptr, dinv, col);
    k_prescale  <<<(NN * 16 + 255) / 256, 256, 0, stream>>>(x, dinv, xs);

    k_gather1x  <<<(NN * 64 + 255) / 256, 256, 0, stream>>>(rowptr, col, xs, dinv, agg1x);
    k_gemm12    <<<(NN + 63) / 64, 256, 0, stream>>>(agg1x, W1h, W1l, b1, W2h, W2l, dinv, y2);
    k_gather2_final<<<(NN * 64 + 255) / 256, 256, 0, stream>>>(rowptr, col, y2, dinv,
                                                               b2, Wfc, bfc, out);
}

// Round 5
// 254.918 us; speedup vs baseline: 1.4873x; 1.0261x over previous
//
#include <hip/hip_runtime.h>

// ProteinGCN: 2x GCNConv(+relu) + FC head. N=100k, E=1.6M, 64->128->64->1.
// Round 10: fp16 rows halved gather traffic (190->85MB) but time only fell
// 62->50.5us: gathers are latency/transaction-bound (HBM 22%, VALU 46%,
// occ 70% -- nothing saturated; 8 edges in flight, col->row chain per
// window, 64-bit per-lane addressing). Raise MLP + cut addr VALU:
// (1) 4-deep unroll (16-edge window, 4 independent col->row chains),
// (2) col[] stores byte offsets (src*128; both tables are 128B/row) so the
// row address is one 32-bit add onto a hoisted per-lane base,
// (3) 2-deep mid cleanup for the Poisson(16) tail.
// CSR: two-level bucket scheme (r8). GEMMs: split-bf16 MFMA (r6/7), fp16
// y2 epilogue (r9).

constexpr int NN = 100000;
constexpr int NE = 1600000;
constexpr int D0 = 64;   // input dim
constexpr int D1 = 128;  // hidden 1
constexpr int D2 = 64;   // hidden 2
constexpr int NB = (NN + 255) / 256;  // 391 buckets
constexpr int TILE = 8192;            // edges per k_part/k_bcount block
constexpr int H1STRIDE = 132;         // h1 LDS row stride (u32)

typedef unsigned short u16;
typedef unsigned int u32;
typedef __attribute__((ext_vector_type(8))) short short8;  // 8 bf16 (4 VGPR)
typedef __attribute__((ext_vector_type(4))) float f32x4;
typedef _Float16 h4 __attribute__((ext_vector_type(4)));   // 4 fp16 = 8 B

// ---------------- CSR build ----------------

__global__ __launch_bounds__(256) void k_zero_b(int* __restrict__ g) {
    int i = blockIdx.x * 256 + threadIdx.x;
    if (i < 512) g[i] = 0;
}

// per-tile LDS histogram of dst-buckets -> global bucket counts
__global__ __launch_bounds__(256) void k_bcount(const int* __restrict__ dst,
                                                int* __restrict__ gbcnt) {
    __shared__ int cnt_s[NB];
    int tid = threadIdx.x;
    int e0 = blockIdx.x * TILE;
    int ecnt = NE - e0 < TILE ? NE - e0 : TILE;
    for (int i = tid; i < NB; i += 256) cnt_s[i] = 0;
    __syncthreads();
    for (int i = tid; i < ecnt; i += 256)
        atomicAdd(&cnt_s[dst[e0 + i] >> 8], 1);
    __syncthreads();
    for (int i = tid; i < NB; i += 256) {
        int c = cnt_s[i];
        if (c) atomicAdd(&gbcnt[i], c);
    }
}

// scan 391 bucket counts -> bucket bases (bsum, bsum[NB]=NE) + part cursors
__global__ __launch_bounds__(512) void k_scan_bsum(const int* __restrict__ gbcnt,
                                                   int* __restrict__ bsum,
                                                   int* __restrict__ gcur) {
    __shared__ int s[512];
    int tid = threadIdx.x;
    int v = (tid < NB) ? gbcnt[tid] : 0;
    s[tid] = v;
    __syncthreads();
#pragma unroll
    for (int off = 1; off < 512; off <<= 1) {
        int t = (tid >= off) ? s[tid - off] : 0;
        __syncthreads();
        s[tid] += t;
        __syncthreads();
    }
    int ex = s[tid] - v;  // exclusive scan
    if (tid <= NB) bsum[tid] = ex;   // bsum[NB] == NE
    if (tid < NB) gcur[tid] = ex;
}

// ---- partition edges into dst-buckets, packed (dl<<24)|src ----
__global__ __launch_bounds__(256) void k_part(const int* __restrict__ src,
                                              const int* __restrict__ dst,
                                              int* __restrict__ gcur,
                                              unsigned* __restrict__ packed) {
    __shared__ int cnt_s[NB];
    __shared__ int gbase_s[NB];
    __shared__ int cur_s[NB];
    int tid = threadIdx.x;
    int e0 = blockIdx.x * TILE;
    int ecnt = NE - e0 < TILE ? NE - e0 : TILE;
    for (int i = tid; i < NB; i += 256) cnt_s[i] = 0;
    __syncthreads();
    for (int i = tid; i < ecnt; i += 256)
        atomicAdd(&cnt_s[dst[e0 + i] >> 8], 1);
    __syncthreads();
    for (int i = tid; i < NB; i += 256) {
        int c = cnt_s[i];
        gbase_s[i] = c ? atomicAdd(&gcur[i], c) : 0;
        cur_s[i] = 0;
    }
    __syncthreads();
    for (int i = tid; i < ecnt; i += 256) {
        int d = dst[e0 + i];
        int s = src[e0 + i];
        int b = d >> 8;
        int slot = atomicAdd(&cur_s[b], 1);
        packed[gbase_s[b] + slot] = ((unsigned)(d & 255) << 24) | (unsigned)s;
    }
}

// ---- one block per bucket: node histogram -> dinv + rowptr, scatter col ----
// col stores BYTE offsets (src*128): both gather tables are 128 B/row.
__global__ __launch_bounds__(256) void k_bucket(const int* __restrict__ bsum,
                                                const unsigned* __restrict__ packed,
                                                int* __restrict__ rowptr,
                                                float* __restrict__ dinv,
                                                int* __restrict__ col) {
    __shared__ int hist[256];
    __shared__ int s[256];
    __shared__ int cur[256];
    int b = blockIdx.x;
    int tid = threadIdx.x;
    int e0 = bsum[b], e1 = bsum[b + 1];
    hist[tid] = 0;
    __syncthreads();
    for (int e = e0 + tid; e < e1; e += 256)
        atomicAdd(&hist[packed[e] >> 24], 1);
    __syncthreads();
    int v = hist[tid];
    int n = (b << 8) + tid;
    if (n < NN) dinv[n] = rsqrtf((float)(v + 1));
    // exclusive scan of per-node counts
    s[tid] = v;
    __syncthreads();
#pragma unroll
    for (int off = 1; off < 256; off <<= 1) {
        int t = (tid >= off) ? s[tid - off] : 0;
        __syncthreads();
        s[tid] += t;
        __syncthreads();
    }
    int base = e0 + s[tid] - v;
    if (n <= NN) rowptr[n] = base;   // n==NN (last bucket) lands on e1==NE
    cur[tid] = base;
    __syncthreads();
    for (int e = e0 + tid; e < e1; e += 256) {
        unsigned p = packed[e];
        int pos = atomicAdd(&cur[p >> 24], 1);
        col[pos] = (int)((p & 0xFFFFFFu) << 7);  // src * 128 byte offset
    }
}

// ---------------- helpers ----------------

__device__ __forceinline__ float4 scale4(const float4& a, float s) {
    return float4{a.x * s, a.y * s, a.z * s, a.w * s};
}

__device__ __forceinline__ void addh4(float4& a, uint2 u) {
    h4 h = *(h4*)&u;
    a.x += (float)h[0]; a.y += (float)h[1]; a.z += (float)h[2]; a.w += (float)h[3];
}

__device__ __forceinline__ uint2 packh4(const float4& v) {
    h4 h;
    h[0] = (_Float16)v.x; h[1] = (_Float16)v.y;
    h[2] = (_Float16)v.z; h[3] = (_Float16)v.w;
    return *(uint2*)&h;
}

__device__ __forceinline__ void xor_reduce4(float4& a, int mask) {
    a.x += __shfl_xor(a.x, mask, 64);
    a.y += __shfl_xor(a.y, mask, 64);
    a.z += __shfl_xor(a.z, mask, 64);
    a.w += __shfl_xor(a.w, mask, 64);
}

// bf16 RNE conversion + back
__device__ __forceinline__ u16 f2bf(float f) {
    u32 u = __float_as_uint(f);
    return (u16)((u + 0x7fffu + ((u >> 16) & 1u)) >> 16);
}
__device__ __forceinline__ float bf2f(u16 h) {
    return __uint_as_float(((u32)h) << 16);
}

// ---------------- prescale: xs = fp16(x * dinv) ----------------
__global__ __launch_bounds__(256) void k_prescale(const float* __restrict__ x,
                                                  const float* __restrict__ dinv,
                                                  u16* __restrict__ xs) {
    int i = blockIdx.x * 256 + threadIdx.x;  // float4 / uint2 index
    if (i >= NN * 16) return;
    float di = dinv[i >> 4];
    ((uint2*)xs)[i] = packh4(scale4(((const float4*)x)[i], di));
}

// ---------------- layer-1 gather on prescaled fp16 xs ----------------
// agg[d] = dinv_d * ( xs[d] + sum_{s in in(d)} xs[s] )  (fp32 accum)
// colb = byte offsets; per-lane base xs + f4*8 hoisted -> 32-bit voffset adds.
__global__ __launch_bounds__(256) void k_gather1x(const int* __restrict__ rowptr,
                                                  const int* __restrict__ colb,
                                                  const u16* __restrict__ xs,
                                                  const float* __restrict__ dinv,
                                                  float* __restrict__ agg) {
    int wave = (blockIdx.x * 256 + threadIdx.x) >> 6;
    int lane = threadIdx.x & 63;
    if (wave >= NN) return;
    int f4 = lane & 15;   // uint2 (4-half) index within 64-half row
    int es = lane >> 4;   // edge sublane 0..3
    int r0 = rowptr[wave], r1 = rowptr[wave + 1];
    const char* xsb = (const char*)xs + f4 * 8;
    float4 acc{0, 0, 0, 0};
    if (es == 0) addh4(acc, *(const uint2*)(xsb + (size_t)wave * 128));  // self loop
    int e = r0 + es;
    // 4-deep: 16-edge window, 4 independent col->row chains
    for (; e + 12 < r1; e += 16) {
        int c0 = colb[e];
        int c1 = colb[e + 4];
        int c2 = colb[e + 8];
        int c3 = colb[e + 12];
        uint2 v0 = *(const uint2*)(xsb + c0);
        uint2 v1 = *(const uint2*)(xsb + c1);
        uint2 v2 = *(const uint2*)(xsb + c2);
        uint2 v3 = *(const uint2*)(xsb + c3);
        addh4(acc, v0); addh4(acc, v1); addh4(acc, v2); addh4(acc, v3);
    }
    // 2-deep cleanup
    for (; e + 4 < r1; e += 8) {
        int c0 = colb[e];
        int c1 = colb[e + 4];
        uint2 v0 = *(const uint2*)(xsb + c0);
        uint2 v1 = *(const uint2*)(xsb + c1);
        addh4(acc, v0); addh4(acc, v1);
    }
    for (; e < r1; e += 4)
        addh4(acc, *(const uint2*)(xsb + colb[e]));
    xor_reduce4(acc, 16);
    xor_reduce4(acc, 32);
    if (es == 0)
        ((float4*)agg)[(size_t)wave * 16 + f4] = scale4(acc, dinv[wave]);
}

// ---------------- weight pre-split into MFMA B-fragment order ----------------
// B-fragment (16x16x32 bf16): lane l holds B[k][col], col=l&15, k=(l>>4)*8+j.
// W1 frags: [(s*8+t)*64 + l]*8 + j  (s: k-step 0..1, t: n-tile 0..7)
// W2 frags: [(s*4+t)*64 + l]*8 + j  (s: k-step 0..3, t: n-tile 0..3)
__global__ __launch_bounds__(256) void k_splitW(const float* __restrict__ W1,
                                                const float* __restrict__ W2,
                                                u16* __restrict__ W1h, u16* __restrict__ W1l,
                                                u16* __restrict__ W2h, u16* __restrict__ W2l) {
    int i = blockIdx.x * 256 + threadIdx.x;  // 0..8191
    if (i >= 8192) return;
    int j = i & 7;
    int l = (i >> 3) & 63;
    int ts = i >> 9;                 // 0..15
    int kf = ((l >> 4) << 3) + j;    // k within 32-step
    int cl = l & 15;
    {   // W1 [64][128]: ts = s*8 + t
        int s = ts >> 3, t = ts & 7;
        float w = W1[(s * 32 + kf) * D1 + t * 16 + cl];
        u16 h = f2bf(w);
        W1h[i] = h;
        W1l[i] = f2bf(w - bf2f(h));
    }
    {   // W2 [128][64]: ts = s*4 + t
        int s = ts >> 2, t = ts & 3;
        float w = W2[(s * 32 + kf) * D2 + t * 16 + cl];
        u16 h = f2bf(w);
        W2h[i] = h;
        W2l[i] = f2bf(w - bf2f(h));
    }
}

// ---------------- fused GEMM1 + GEMM2 via split-bf16 MFMA ----------------
// h1 = relu(agg @ W1 + b1)   (64 -> 128, packed hi/lo bf16 in LDS)
// y2 = fp16((h1 @ W2) * dinv)  (128 -> 64)
// Block: 64 nodes, 4 waves; wave w owns node rows w*16..w*16+15.
__global__ __launch_bounds__(256) void k_gemm12(const float* __restrict__ agg,
                                                const u16* __restrict__ W1h,
                                                const u16* __restrict__ W1l,
                                                const float* __restrict__ b1,
                                                const u16* __restrict__ W2h,
                                                const u16* __restrict__ W2l,
                                                const float* __restrict__ dinv,
                                                u16* __restrict__ y2) {
    __shared__ u32 h1s[64 * H1STRIDE];  // packed (hi | lo<<16), 33.8 KB
    int tid = threadIdx.x;
    int l = tid & 63;
    int wv = tid >> 6;
    int n_base = blockIdx.x * 64;
    int row_a = l & 15;           // A-operand row within 16-tile
    int kg = (l >> 4) << 3;       // k offset within 32-step: 0,8,16,24
    int crow = (l >> 4) * 4;      // C/D row base: (lane>>4)*4

    // ---- phase A: h1 = relu(agg @ W1 + b1) ----
    short8 Ah[2], Al[2];
#pragma unroll
    for (int s = 0; s < 2; ++s) {
        int an = n_base + wv * 16 + row_a;
        if (an >= NN) an = NN - 1;  // clamp: dup rows, outputs discarded
        const float* ap = agg + (size_t)an * D0 + s * 32 + kg;
        f32x4 v0 = *(const f32x4*)ap;
        f32x4 v1 = *(const f32x4*)(ap + 4);
#pragma unroll
        for (int j = 0; j < 4; ++j) {
            u16 h0 = f2bf(v0[j]);
            Ah[s][j] = (short)h0;
            Al[s][j] = (short)f2bf(v0[j] - bf2f(h0));
            u16 h1b = f2bf(v1[j]);
            Ah[s][j + 4] = (short)h1b;
            Al[s][j + 4] = (short)f2bf(v1[j] - bf2f(h1b));
        }
    }
#pragma unroll
    for (int t = 0; t < 8; ++t) {
        f32x4 acc = {0.f, 0.f, 0.f, 0.f};
#pragma unroll
        for (int s = 0; s < 2; ++s) {
            short8 Bh = *(const short8*)(W1h + ((size_t)(s * 8 + t) * 64 + l) * 8);
            short8 Bl = *(const short8*)(W1l + ((size_t)(s * 8 + t) * 64 + l) * 8);
            acc = __builtin_amdgcn_mfma_f32_16x16x32_bf16(Ah[s], Bh, acc, 0, 0, 0);
            acc = __builtin_amdgcn_mfma_f32_16x16x32_bf16(Ah[s], Bl, acc, 0, 0, 0);
            acc = __builtin_amdgcn_mfma_f32_16x16x32_bf16(Al[s], Bh, acc, 0, 0, 0);
        }
        // epilogue: +b1, relu, split-pack to LDS (C/D: row=(l>>4)*4+r, col=l&15)
        float bb = b1[t * 16 + (l & 15)];
        int kcol = t * 16 + (l & 15);  // h1 feature index = GEMM2 k
#pragma unroll
        for (int r = 0; r < 4; ++r) {
            int row = wv * 16 + crow + r;  // node row in 64-tile
            float v = fmaxf(acc[r] + bb, 0.f);
            u16 h = f2bf(v);
            u16 lo = f2bf(v - bf2f(h));
            h1s[row * H1STRIDE + kcol] = (u32)h | ((u32)lo << 16);
        }
    }
    __syncthreads();

    // ---- phase B: y2 = fp16((h1 @ W2) * dinv) ----
    short8 A2h[4], A2l[4];
#pragma unroll
    for (int s = 0; s < 4; ++s) {
        int row = wv * 16 + row_a;
        const u32* hp = &h1s[row * H1STRIDE + s * 32 + kg];
        uint4 p0 = *(const uint4*)hp;
        uint4 p1 = *(const uint4*)(hp + 4);
        u32 pv[8] = {p0.x, p0.y, p0.z, p0.w, p1.x, p1.y, p1.z, p1.w};
#pragma unroll
        for (int j = 0; j < 8; ++j) {
            A2h[s][j] = (short)(pv[j] & 0xffffu);
            A2l[s][j] = (short)(pv[j] >> 16);
        }
    }
#pragma unroll
    for (int t = 0; t < 4; ++t) {
        f32x4 acc = {0.f, 0.f, 0.f, 0.f};
#pragma unroll
        for (int s = 0; s < 4; ++s) {
            short8 Bh = *(const short8*)(W2h + ((size_t)(s * 4 + t) * 64 + l) * 8);
            short8 Bl = *(const short8*)(W2l + ((size_t)(s * 4 + t) * 64 + l) * 8);
            acc = __builtin_amdgcn_mfma_f32_16x16x32_bf16(A2h[s], Bh, acc, 0, 0, 0);
            acc = __builtin_amdgcn_mfma_f32_16x16x32_bf16(A2h[s], Bl, acc, 0, 0, 0);
            acc = __builtin_amdgcn_mfma_f32_16x16x32_bf16(A2l[s], Bh, acc, 0, 0, 0);
        }
#pragma unroll
        for (int r = 0; r < 4; ++r) {
            int n = n_base + wv * 16 + crow + r;
            if (n < NN) {
                _Float16 hf = (_Float16)(acc[r] * dinv[n]);
                y2[(size_t)n * D2 + t * 16 + (l & 15)] = *(u16*)&hf;
            }
        }
    }
}

// ---------------- layer-2 gather fused with FC head ----------------
// acc = y2[d] + sum y2[s]; out[d] = relu(acc*dinv_d + b2) . Wfc + bfc
__global__ __launch_bounds__(256) void k_gather2_final(const int* __restrict__ rowptr,
                                                       const int* __restrict__ colb,
                                                       const u16* __restrict__ y2,
                                                       const float* __restrict__ dinv,
                                                       const float* __restrict__ b2,
                                                       const float* __restrict__ Wfc,
                                                       const float* __restrict__ bfc,
                                                       float* __restrict__ out) {
    int wave = (blockIdx.x * 256 + threadIdx.x) >> 6;
    int lane = threadIdx.x & 63;
    if (wave >= NN) return;
    int f4 = lane & 15;
    int es = lane >> 4;
    int r0 = rowptr[wave], r1 = rowptr[wave + 1];
    const char* y2b = (const char*)y2 + f4 * 8;
    float4 acc{0, 0, 0, 0};
    if (es == 0) addh4(acc, *(const uint2*)(y2b + (size_t)wave * 128));  // self loop
    int e = r0 + es;
    for (; e + 12 < r1; e += 16) {
        int c0 = colb[e];
        int c1 = colb[e + 4];
        int c2 = colb[e + 8];
        int c3 = colb[e + 12];
        uint2 v0 = *(const uint2*)(y2b + c0);
        uint2 v1 = *(const uint2*)(y2b + c1);
        uint2 v2 = *(const uint2*)(y2b + c2);
        uint2 v3 = *(const uint2*)(y2b + c3);
        addh4(acc, v0); addh4(acc, v1); addh4(acc, v2); addh4(acc, v3);
    }
    for (; e + 4 < r1; e += 8) {
        int c0 = colb[e];
        int c1 = colb[e + 4];
        uint2 v0 = *(const uint2*)(y2b + c0);
        uint2 v1 = *(const uint2*)(y2b + c1);
        addh4(acc, v0); addh4(acc, v1);
    }
    for (; e < r1; e += 4)
        addh4(acc, *(const uint2*)(y2b + colb[e]));
    xor_reduce4(acc, 16);
    xor_reduce4(acc, 32);
    // every lane now holds the feature-group sum for its f4 (4 copies)
    float di = dinv[wave];
    float4 b = ((const float4*)b2)[f4];
    float4 w = ((const float4*)Wfc)[f4];
    float p = fmaxf(fmaf(acc.x, di, b.x), 0.f) * w.x
            + fmaxf(fmaf(acc.y, di, b.y), 0.f) * w.y
            + fmaxf(fmaf(acc.z, di, b.z), 0.f) * w.z
            + fmaxf(fmaf(acc.w, di, b.w), 0.f) * w.w;
    // sum the 16 f4 groups (each 16-lane block holds all 16 f4 values)
    p += __shfl_xor(p, 1, 64);
    p += __shfl_xor(p, 2, 64);
    p += __shfl_xor(p, 4, 64);
    p += __shfl_xor(p, 8, 64);
    if (lane == 0) out[wave] = p + bfc[0];
}

extern "C" void kernel_launch(void* const* d_in, const int* in_sizes, int n_in,
                              void* d_out, int out_size, void* d_ws, size_t ws_size,
                              hipStream_t stream) {
    const float* x   = (const float*)d_in[0];
    const int*   ei  = (const int*)d_in[1];   // [2, E] int
    const float* W1  = (const float*)d_in[2];
    const float* b1  = (const float*)d_in[3];
    const float* W2  = (const float*)d_in[4];
    const float* b2  = (const float*)d_in[5];
    const float* Wfc = (const float*)d_in[6];
    const float* bfc = (const float*)d_in[7];
    float* out = (float*)d_out;

    const int* src = ei;
    const int* dst = ei + NE;

    char* ws = (char*)d_ws;
    size_t o = 0;
    auto alloc = [&](size_t bytes) { char* p = ws + o; o += (bytes + 255) & ~size_t(255); return p; };
    int*   scratch = (int*)alloc(NN * 4);      // 400 KB: gbcnt + W-split buffers
    int*   rowptr = (int*)alloc((NN + 1) * 4);
    int*   bsum   = (int*)alloc(512 * 4);
    int*   gcur   = (int*)alloc(NB * 4);
    float* dinv   = (float*)alloc(NN * 4);
    int*   col    = (int*)alloc((size_t)NE * 4);
    u16*   xs     = (u16*)alloc((size_t)NN * D0 * 2);    // 12.8 MB fp16
    float* agg1x  = (float*)alloc((size_t)NN * D0 * 4);  // 25.6 MB fp32
    u16*   y2     = (u16*)alloc((size_t)NN * D2 * 2);    // 12.8 MB fp16
    unsigned* packed = (unsigned*)agg1x;  // dead before k_gather1x writes agg
    // carve scratch: bucket counts (512 ints) then the 4 x 16 KB weight splits
    int* gbcnt = scratch;
    u16* W1h = (u16*)(scratch + 512);
    u16* W1l = W1h + 8192;
    u16* W2h = W1l + 8192;
    u16* W2l = W2h + 8192;

    const int NT = (NE + TILE - 1) / TILE;  // 196 tiles

    k_zero_b    <<<2, 256, 0, stream>>>(gbcnt);
    k_splitW    <<<32, 256, 0, stream>>>(W1, W2, W1h, W1l, W2h, W2l);
    k_bcount    <<<NT, 256, 0, stream>>>(dst, gbcnt);
    k_scan_bsum <<<1, 512, 0, stream>>>(gbcnt, bsum, gcur);
    k_part      <<<NT, 256, 0, stream>>>(src, dst, gcur, packed);
    k_bucket    <<<NB, 256, 0, stream>>>(bsum, packed, rowptr, dinv, col);
    k_prescale  <<<(NN * 16 + 255) / 256, 256, 0, stream>>>(x, dinv, xs);

    k_gather1x  <<<(NN * 64 + 255) / 256, 256, 0, stream>>>(rowptr, col, xs, dinv, agg1x);
    k_gemm12    <<<(NN + 63) / 64, 256, 0, stream>>>(agg1x, W1h, W1l, b1, W2h, W2l, dinv, y2);
    k_gather2_final<<<(NN * 64 + 255) / 256, 256, 0, stream>>>(rowptr, col, y2, dinv,
                                                               b2, Wfc, bfc, out);
}

// Round 6
// 249.747 us; speedup vs baseline: 1.5181x; 1.0207x over previous
//
#include <hip/hip_runtime.h>

// ProteinGCN: 2x GCNConv(+relu) + FC head. N=100k, E=1.6M, 64->128->64->1.
// Round 11: gather evidence across r9/r10 (2.2x traffic cut -> 1.23x time;
// 4-deep unroll+32b addressing -> 1.05x) says the wall is per-INSTRUCTION
// divergent-VMEM processing, not bytes/lines/latency. Invariant so far:
// 16 lanes/edge -> 4 edges per gather instr (400K instrs/pass). This round:
// 16 B/lane dwordx4 gathers, 8 lanes/edge -> 8 edges/instr (200K instrs),
// same bytes+lines+numerics. Lane map: f8=lane&7 (16B chunk), es=lane>>3;
// float8 accum; xor-reduce masks 8/16/32; head reduce masks 1/2/4.
// Discriminator: null result => instruction-rate theory wrong => next round
// XCD-sliced feature chunks (3.2MB slice per L2 via blockIdx swizzle).
// CSR: two-level bucket (r8), byte-offset col (r10). GEMMs: split-bf16 MFMA
// (r6/7), fp16 xs/y2 rows (r9).

constexpr int NN = 100000;
constexpr int NE = 1600000;
constexpr int D0 = 64;   // input dim
constexpr int D1 = 128;  // hidden 1
constexpr int D2 = 64;   // hidden 2
constexpr int NB = (NN + 255) / 256;  // 391 buckets
constexpr int TILE = 8192;            // edges per k_part/k_bcount block
constexpr int H1STRIDE = 132;         // h1 LDS row stride (u32)

typedef unsigned short u16;
typedef unsigned int u32;
typedef __attribute__((ext_vector_type(8))) short short8;  // 8 bf16 (4 VGPR)
typedef __attribute__((ext_vector_type(4))) float f32x4;
typedef _Float16 h4 __attribute__((ext_vector_type(4)));   // 4 fp16 = 8 B

// ---------------- CSR build ----------------

__global__ __launch_bounds__(256) void k_zero_b(int* __restrict__ g) {
    int i = blockIdx.x * 256 + threadIdx.x;
    if (i < 512) g[i] = 0;
}

// per-tile LDS histogram of dst-buckets -> global bucket counts
__global__ __launch_bounds__(256) void k_bcount(const int* __restrict__ dst,
                                                int* __restrict__ gbcnt) {
    __shared__ int cnt_s[NB];
    int tid = threadIdx.x;
    int e0 = blockIdx.x * TILE;
    int ecnt = NE - e0 < TILE ? NE - e0 : TILE;
    for (int i = tid; i < NB; i += 256) cnt_s[i] = 0;
    __syncthreads();
    for (int i = tid; i < ecnt; i += 256)
        atomicAdd(&cnt_s[dst[e0 + i] >> 8], 1);
    __syncthreads();
    for (int i = tid; i < NB; i += 256) {
        int c = cnt_s[i];
        if (c) atomicAdd(&gbcnt[i], c);
    }
}

// scan 391 bucket counts -> bucket bases (bsum, bsum[NB]=NE) + part cursors
__global__ __launch_bounds__(512) void k_scan_bsum(const int* __restrict__ gbcnt,
                                                   int* __restrict__ bsum,
                                                   int* __restrict__ gcur) {
    __shared__ int s[512];
    int tid = threadIdx.x;
    int v = (tid < NB) ? gbcnt[tid] : 0;
    s[tid] = v;
    __syncthreads();
#pragma unroll
    for (int off = 1; off < 512; off <<= 1) {
        int t = (tid >= off) ? s[tid - off] : 0;
        __syncthreads();
        s[tid] += t;
        __syncthreads();
    }
    int ex = s[tid] - v;  // exclusive scan
    if (tid <= NB) bsum[tid] = ex;   // bsum[NB] == NE
    if (tid < NB) gcur[tid] = ex;
}

// ---- partition edges into dst-buckets, packed (dl<<24)|src ----
__global__ __launch_bounds__(256) void k_part(const int* __restrict__ src,
                                              const int* __restrict__ dst,
                                              int* __restrict__ gcur,
                                              unsigned* __restrict__ packed) {
    __shared__ int cnt_s[NB];
    __shared__ int gbase_s[NB];
    __shared__ int cur_s[NB];
    int tid = threadIdx.x;
    int e0 = blockIdx.x * TILE;
    int ecnt = NE - e0 < TILE ? NE - e0 : TILE;
    for (int i = tid; i < NB; i += 256) cnt_s[i] = 0;
    __syncthreads();
    for (int i = tid; i < ecnt; i += 256)
        atomicAdd(&cnt_s[dst[e0 + i] >> 8], 1);
    __syncthreads();
    for (int i = tid; i < NB; i += 256) {
        int c = cnt_s[i];
        gbase_s[i] = c ? atomicAdd(&gcur[i], c) : 0;
        cur_s[i] = 0;
    }
    __syncthreads();
    for (int i = tid; i < ecnt; i += 256) {
        int d = dst[e0 + i];
        int s = src[e0 + i];
        int b = d >> 8;
        int slot = atomicAdd(&cur_s[b], 1);
        packed[gbase_s[b] + slot] = ((unsigned)(d & 255) << 24) | (unsigned)s;
    }
}

// ---- one block per bucket: node histogram -> dinv + rowptr, scatter col ----
// col stores BYTE offsets (src*128): both gather tables are 128 B/row.
__global__ __launch_bounds__(256) void k_bucket(const int* __restrict__ bsum,
                                                const unsigned* __restrict__ packed,
                                                int* __restrict__ rowptr,
                                                float* __restrict__ dinv,
                                                int* __restrict__ col) {
    __shared__ int hist[256];
    __shared__ int s[256];
    __shared__ int cur[256];
    int b = blockIdx.x;
    int tid = threadIdx.x;
    int e0 = bsum[b], e1 = bsum[b + 1];
    hist[tid] = 0;
    __syncthreads();
    for (int e = e0 + tid; e < e1; e += 256)
        atomicAdd(&hist[packed[e] >> 24], 1);
    __syncthreads();
    int v = hist[tid];
    int n = (b << 8) + tid;
    if (n < NN) dinv[n] = rsqrtf((float)(v + 1));
    // exclusive scan of per-node counts
    s[tid] = v;
    __syncthreads();
#pragma unroll
    for (int off = 1; off < 256; off <<= 1) {
        int t = (tid >= off) ? s[tid - off] : 0;
        __syncthreads();
        s[tid] += t;
        __syncthreads();
    }
    int base = e0 + s[tid] - v;
    if (n <= NN) rowptr[n] = base;   // n==NN (last bucket) lands on e1==NE
    cur[tid] = base;
    __syncthreads();
    for (int e = e0 + tid; e < e1; e += 256) {
        unsigned p = packed[e];
        int pos = atomicAdd(&cur[p >> 24], 1);
        col[pos] = (int)((p & 0xFFFFFFu) << 7);  // src * 128 byte offset
    }
}

// ---------------- helpers ----------------

__device__ __forceinline__ float4 scale4(const float4& a, float s) {
    return float4{a.x * s, a.y * s, a.z * s, a.w * s};
}

// add 8 fp16 (uint4) into two float4 accumulators
__device__ __forceinline__ void addh8(float4& a, float4& b, uint4 u) {
    h4 h0 = *(h4*)&u.x;   // u.x,u.y
    h4 h1 = *(h4*)&u.z;   // u.z,u.w
    a.x += (float)h0[0]; a.y += (float)h0[1]; a.z += (float)h0[2]; a.w += (float)h0[3];
    b.x += (float)h1[0]; b.y += (float)h1[1]; b.z += (float)h1[2]; b.w += (float)h1[3];
}

__device__ __forceinline__ uint2 packh4(const float4& v) {
    h4 h;
    h[0] = (_Float16)v.x; h[1] = (_Float16)v.y;
    h[2] = (_Float16)v.z; h[3] = (_Float16)v.w;
    return *(uint2*)&h;
}

__device__ __forceinline__ void xor_reduce8(float4& a, float4& b, int mask) {
    a.x += __shfl_xor(a.x, mask, 64);
    a.y += __shfl_xor(a.y, mask, 64);
    a.z += __shfl_xor(a.z, mask, 64);
    a.w += __shfl_xor(a.w, mask, 64);
    b.x += __shfl_xor(b.x, mask, 64);
    b.y += __shfl_xor(b.y, mask, 64);
    b.z += __shfl_xor(b.z, mask, 64);
    b.w += __shfl_xor(b.w, mask, 64);
}

// bf16 RNE conversion + back
__device__ __forceinline__ u16 f2bf(float f) {
    u32 u = __float_as_uint(f);
    return (u16)((u + 0x7fffu + ((u >> 16) & 1u)) >> 16);
}
__device__ __forceinline__ float bf2f(u16 h) {
    return __uint_as_float(((u32)h) << 16);
}

// ---------------- prescale: xs = fp16(x * dinv) ----------------
__global__ __launch_bounds__(256) void k_prescale(const float* __restrict__ x,
                                                  const float* __restrict__ dinv,
                                                  u16* __restrict__ xs) {
    int i = blockIdx.x * 256 + threadIdx.x;  // float4 / uint2 index
    if (i >= NN * 16) return;
    float di = dinv[i >> 4];
    ((uint2*)xs)[i] = packh4(scale4(((const float4*)x)[i], di));
}

// ---------------- layer-1 gather on prescaled fp16 xs ----------------
// agg[d] = dinv_d * ( xs[d] + sum_{s in in(d)} xs[s] )  (fp32 accum)
// 16 B/lane dwordx4: f8=lane&7 (16B chunk of 128B row), es=lane>>3 -> 8
// edges per instruction. 2-deep window (16 edges), 1-deep cleanup.
__global__ __launch_bounds__(256) void k_gather1x(const int* __restrict__ rowptr,
                                                  const int* __restrict__ colb,
                                                  const u16* __restrict__ xs,
                                                  const float* __restrict__ dinv,
                                                  float* __restrict__ agg) {
    int wave = (blockIdx.x * 256 + threadIdx.x) >> 6;
    int lane = threadIdx.x & 63;
    if (wave >= NN) return;
    int f8 = lane & 7;    // 16B chunk index within 128B row
    int es = lane >> 3;   // edge sublane 0..7
    int r0 = rowptr[wave], r1 = rowptr[wave + 1];
    const char* xsb = (const char*)xs + f8 * 16;
    float4 accA{0, 0, 0, 0}, accB{0, 0, 0, 0};
    if (es == 0) addh8(accA, accB, *(const uint4*)(xsb + (size_t)wave * 128));  // self loop
    int e = r0 + es;
    // 2-deep: 16-edge window, 2 independent col->row chains
    for (; e + 8 < r1; e += 16) {
        int c0 = colb[e];
        int c1 = colb[e + 8];
        uint4 v0 = *(const uint4*)(xsb + c0);
        uint4 v1 = *(const uint4*)(xsb + c1);
        addh8(accA, accB, v0);
        addh8(accA, accB, v1);
    }
    for (; e < r1; e += 8)
        addh8(accA, accB, *(const uint4*)(xsb + colb[e]));
    xor_reduce8(accA, accB, 8);
    xor_reduce8(accA, accB, 16);
    xor_reduce8(accA, accB, 32);
    if (es == 0) {
        float di = dinv[wave];
        float4* ag = (float4*)agg + (size_t)wave * 16 + f8 * 2;
        ag[0] = scale4(accA, di);
        ag[1] = scale4(accB, di);
    }
}

// ---------------- weight pre-split into MFMA B-fragment order ----------------
// B-fragment (16x16x32 bf16): lane l holds B[k][col], col=l&15, k=(l>>4)*8+j.
// W1 frags: [(s*8+t)*64 + l]*8 + j  (s: k-step 0..1, t: n-tile 0..7)
// W2 frags: [(s*4+t)*64 + l]*8 + j  (s: k-step 0..3, t: n-tile 0..3)
__global__ __launch_bounds__(256) void k_splitW(const float* __restrict__ W1,
                                                const float* __restrict__ W2,
                                                u16* __restrict__ W1h, u16* __restrict__ W1l,
                                                u16* __restrict__ W2h, u16* __restrict__ W2l) {
    int i = blockIdx.x * 256 + threadIdx.x;  // 0..8191
    if (i >= 8192) return;
    int j = i & 7;
    int l = (i >> 3) & 63;
    int ts = i >> 9;                 // 0..15
    int kf = ((l >> 4) << 3) + j;    // k within 32-step
    int cl = l & 15;
    {   // W1 [64][128]: ts = s*8 + t
        int s = ts >> 3, t = ts & 7;
        float w = W1[(s * 32 + kf) * D1 + t * 16 + cl];
        u16 h = f2bf(w);
        W1h[i] = h;
        W1l[i] = f2bf(w - bf2f(h));
    }
    {   // W2 [128][64]: ts = s*4 + t
        int s = ts >> 2, t = ts & 3;
        float w = W2[(s * 32 + kf) * D2 + t * 16 + cl];
        u16 h = f2bf(w);
        W2h[i] = h;
        W2l[i] = f2bf(w - bf2f(h));
    }
}

// ---------------- fused GEMM1 + GEMM2 via split-bf16 MFMA ----------------
// h1 = relu(agg @ W1 + b1)   (64 -> 128, packed hi/lo bf16 in LDS)
// y2 = fp16((h1 @ W2) * dinv)  (128 -> 64)
// Block: 64 nodes, 4 waves; wave w owns node rows w*16..w*16+15.
__global__ __launch_bounds__(256) void k_gemm12(const float* __restrict__ agg,
                                                const u16* __restrict__ W1h,
                                                const u16* __restrict__ W1l,
                                                const float* __restrict__ b1,
                                                const u16* __restrict__ W2h,
                                                const u16* __restrict__ W2l,
                                                const float* __restrict__ dinv,
                                                u16* __restrict__ y2) {
    __shared__ u32 h1s[64 * H1STRIDE];  // packed (hi | lo<<16), 33.8 KB
    int tid = threadIdx.x;
    int l = tid & 63;
    int wv = tid >> 6;
    int n_base = blockIdx.x * 64;
    int row_a = l & 15;           // A-operand row within 16-tile
    int kg = (l >> 4) << 3;       // k offset within 32-step: 0,8,16,24
    int crow = (l >> 4) * 4;      // C/D row base: (lane>>4)*4

    // ---- phase A: h1 = relu(agg @ W1 + b1) ----
    short8 Ah[2], Al[2];
#pragma unroll
    for (int s = 0; s < 2; ++s) {
        int an = n_base + wv * 16 + row_a;
        if (an >= NN) an = NN - 1;  // clamp: dup rows, outputs discarded
        const float* ap = agg + (size_t)an * D0 + s * 32 + kg;
        f32x4 v0 = *(const f32x4*)ap;
        f32x4 v1 = *(const f32x4*)(ap + 4);
#pragma unroll
        for (int j = 0; j < 4; ++j) {
            u16 h0 = f2bf(v0[j]);
            Ah[s][j] = (short)h0;
            Al[s][j] = (short)f2bf(v0[j] - bf2f(h0));
            u16 h1b = f2bf(v1[j]);
            Ah[s][j + 4] = (short)h1b;
            Al[s][j + 4] = (short)f2bf(v1[j] - bf2f(h1b));
        }
    }
#pragma unroll
    for (int t = 0; t < 8; ++t) {
        f32x4 acc = {0.f, 0.f, 0.f, 0.f};
#pragma unroll
        for (int s = 0; s < 2; ++s) {
            short8 Bh = *(const short8*)(W1h + ((size_t)(s * 8 + t) * 64 + l) * 8);
            short8 Bl = *(const short8*)(W1l + ((size_t)(s * 8 + t) * 64 + l) * 8);
            acc = __builtin_amdgcn_mfma_f32_16x16x32_bf16(Ah[s], Bh, acc, 0, 0, 0);
            acc = __builtin_amdgcn_mfma_f32_16x16x32_bf16(Ah[s], Bl, acc, 0, 0, 0);
            acc = __builtin_amdgcn_mfma_f32_16x16x32_bf16(Al[s], Bh, acc, 0, 0, 0);
        }
        // epilogue: +b1, relu, split-pack to LDS (C/D: row=(l>>4)*4+r, col=l&15)
        float bb = b1[t * 16 + (l & 15)];
        int kcol = t * 16 + (l & 15);  // h1 feature index = GEMM2 k
#pragma unroll
        for (int r = 0; r < 4; ++r) {
            int row = wv * 16 + crow + r;  // node row in 64-tile
            float v = fmaxf(acc[r] + bb, 0.f);
            u16 h = f2bf(v);
            u16 lo = f2bf(v - bf2f(h));
            h1s[row * H1STRIDE + kcol] = (u32)h | ((u32)lo << 16);
        }
    }
    __syncthreads();

    // ---- phase B: y2 = fp16((h1 @ W2) * dinv) ----
    short8 A2h[4], A2l[4];
#pragma unroll
    for (int s = 0; s < 4; ++s) {
        int row = wv * 16 + row_a;
        const u32* hp = &h1s[row * H1STRIDE + s * 32 + kg];
        uint4 p0 = *(const uint4*)hp;
        uint4 p1 = *(const uint4*)(hp + 4);
        u32 pv[8] = {p0.x, p0.y, p0.z, p0.w, p1.x, p1.y, p1.z, p1.w};
#pragma unroll
        for (int j = 0; j < 8; ++j) {
            A2h[s][j] = (short)(pv[j] & 0xffffu);
            A2l[s][j] = (short)(pv[j] >> 16);
        }
    }
#pragma unroll
    for (int t = 0; t < 4; ++t) {
        f32x4 acc = {0.f, 0.f, 0.f, 0.f};
#pragma unroll
        for (int s = 0; s < 4; ++s) {
            short8 Bh = *(const short8*)(W2h + ((size_t)(s * 4 + t) * 64 + l) * 8);
            short8 Bl = *(const short8*)(W2l + ((size_t)(s * 4 + t) * 64 + l) * 8);
            acc = __builtin_amdgcn_mfma_f32_16x16x32_bf16(A2h[s], Bh, acc, 0, 0, 0);
            acc = __builtin_amdgcn_mfma_f32_16x16x32_bf16(A2h[s], Bl, acc, 0, 0, 0);
            acc = __builtin_amdgcn_mfma_f32_16x16x32_bf16(A2l[s], Bh, acc, 0, 0, 0);
        }
#pragma unroll
        for (int r = 0; r < 4; ++r) {
            int n = n_base + wv * 16 + crow + r;
            if (n < NN) {
                _Float16 hf = (_Float16)(acc[r] * dinv[n]);
                y2[(size_t)n * D2 + t * 16 + (l & 15)] = *(u16*)&hf;
            }
        }
    }
}

// ---------------- layer-2 gather fused with FC head ----------------
// acc = y2[d] + sum y2[s]; out[d] = relu(acc*dinv_d + b2) . Wfc + bfc
// Same 8-edges-per-instruction layout as k_gather1x.
__global__ __launch_bounds__(256) void k_gather2_final(const int* __restrict__ rowptr,
                                                       const int* __restrict__ colb,
                                                       const u16* __restrict__ y2,
                                                       const float* __restrict__ dinv,
                                                       const float* __restrict__ b2,
                                                       const float* __restrict__ Wfc,
                                                       const float* __restrict__ bfc,
                                                       float* __restrict__ out) {
    int wave = (blockIdx.x * 256 + threadIdx.x) >> 6;
    int lane = threadIdx.x & 63;
    if (wave >= NN) return;
    int f8 = lane & 7;
    int es = lane >> 3;
    int r0 = rowptr[wave], r1 = rowptr[wave + 1];
    const char* y2b = (const char*)y2 + f8 * 16;
    float4 accA{0, 0, 0, 0}, accB{0, 0, 0, 0};
    if (es == 0) addh8(accA, accB, *(const uint4*)(y2b + (size_t)wave * 128));  // self loop
    int e = r0 + es;
    for (; e + 8 < r1; e += 16) {
        int c0 = colb[e];
        int c1 = colb[e + 8];
        uint4 v0 = *(const uint4*)(y2b + c0);
        uint4 v1 = *(const uint4*)(y2b + c1);
        addh8(accA, accB, v0);
        addh8(accA, accB, v1);
    }
    for (; e < r1; e += 8)
        addh8(accA, accB, *(const uint4*)(y2b + colb[e]));
    xor_reduce8(accA, accB, 8);
    xor_reduce8(accA, accB, 16);
    xor_reduce8(accA, accB, 32);
    // every lane now holds the 8-feature sum for its f8 group
    float di = dinv[wave];
    float4 bA = ((const float4*)b2)[f8 * 2];
    float4 bB = ((const float4*)b2)[f8 * 2 + 1];
    float4 wA = ((const float4*)Wfc)[f8 * 2];
    float4 wB = ((const float4*)Wfc)[f8 * 2 + 1];
    float p = fmaxf(fmaf(accA.x, di, bA.x), 0.f) * wA.x
            + fmaxf(fmaf(accA.y, di, bA.y), 0.f) * wA.y
            + fmaxf(fmaf(accA.z, di, bA.z), 0.f) * wA.z
            + fmaxf(fmaf(accA.w, di, bA.w), 0.f) * wA.w
            + fmaxf(fmaf(accB.x, di, bB.x), 0.f) * wB.x
            + fmaxf(fmaf(accB.y, di, bB.y), 0.f) * wB.y
            + fmaxf(fmaf(accB.z, di, bB.z), 0.f) * wB.z
            + fmaxf(fmaf(accB.w, di, bB.w), 0.f) * wB.w;
    // sum the 8 f8 groups
    p += __shfl_xor(p, 1, 64);
    p += __shfl_xor(p, 2, 64);
    p += __shfl_xor(p, 4, 64);
    if (lane == 0) out[wave] = p + bfc[0];
}

extern "C" void kernel_launch(void* const* d_in, const int* in_sizes, int n_in,
                              void* d_out, int out_size, void* d_ws, size_t ws_size,
                              hipStream_t stream) {
    const float* x   = (const float*)d_in[0];
    const int*   ei  = (const int*)d_in[1];   // [2, E] int
    const float* W1  = (const float*)d_in[2];
    const float* b1  = (const float*)d_in[3];
    const float* W2  = (const float*)d_in[4];
    const float* b2  = (const float*)d_in[5];
    const float* Wfc = (const float*)d_in[6];
    const float* bfc = (const float*)d_in[7];
    float* out = (float*)d_out;

    const int* src = ei;
    const int* dst = ei + NE;

    char* ws = (char*)d_ws;
    size_t o = 0;
    auto alloc = [&](size_t bytes) { char* p = ws + o; o += (bytes + 255) & ~size_t(255); return p; };
    int*   scratch = (int*)alloc(NN * 4);      // 400 KB: gbcnt + W-split buffers
    int*   rowptr = (int*)alloc((NN + 1) * 4);
    int*   bsum   = (int*)alloc(512 * 4);
    int*   gcur   = (int*)alloc(NB * 4);
    float* dinv   = (float*)alloc(NN * 4);
    int*   col    = (int*)alloc((size_t)NE * 4);
    u16*   xs     = (u16*)alloc((size_t)NN * D0 * 2);    // 12.8 MB fp16
    float* agg1x  = (float*)alloc((size_t)NN * D0 * 4);  // 25.6 MB fp32
    u16*   y2     = (u16*)alloc((size_t)NN * D2 * 2);    // 12.8 MB fp16
    unsigned* packed = (unsigned*)agg1x;  // dead before k_gather1x writes agg
    // carve scratch: bucket counts (512 ints) then the 4 x 16 KB weight splits
    int* gbcnt = scratch;
    u16* W1h = (u16*)(scratch + 512);
    u16* W1l = W1h + 8192;
    u16* W2h = W1l + 8192;
    u16* W2l = W2h + 8192;

    const int NT = (NE + TILE - 1) / TILE;  // 196 tiles

    k_zero_b    <<<2, 256, 0, stream>>>(gbcnt);
    k_splitW    <<<32, 256, 0, stream>>>(W1, W2, W1h, W1l, W2h, W2l);
    k_bcount    <<<NT, 256, 0, stream>>>(dst, gbcnt);
    k_scan_bsum <<<1, 512, 0, stream>>>(gbcnt, bsum, gcur);
    k_part      <<<NT, 256, 0, stream>>>(src, dst, gcur, packed);
    k_bucket    <<<NB, 256, 0, stream>>>(bsum, packed, rowptr, dinv, col);
    k_prescale  <<<(NN * 16 + 255) / 256, 256, 0, stream>>>(x, dinv, xs);

    k_gather1x  <<<(NN * 64 + 255) / 256, 256, 0, stream>>>(rowptr, col, xs, dinv, agg1x);
    k_gemm12    <<<(NN + 63) / 64, 256, 0, stream>>>(agg1x, W1h, W1l, b1, W2h, W2l, dinv, y2);
    k_gather2_final<<<(NN * 64 + 255) / 256, 256, 0, stream>>>(rowptr, col, y2, dinv,
                                                               b2, Wfc, bfc, out);
}

// Round 7
// 246.949 us; speedup vs baseline: 1.5353x; 1.0113x over previous
//
#include <hip/hip_runtime.h>

// ProteinGCN: 2x GCNConv(+relu) + FC head. N=100k, E=1.6M, 64->128->64->1.
// Round 12: gather FETCH 85MB == 8 XCDs x ~10.6MB unique table bytes -> the
// random gather sits at the COMPULSORY-MISS floor of the replicated per-XCD
// L2s (85MB/46us = 1.9 TB/s latency-bound miss path). r9-r11 falsified
// bytes/instr/unroll levers. This round: feature-slice the gathered tables
// into 4 slices of 16 feats (32B rows, 3.2MB/slice -- fits a 4MB XCD L2)
// and PIN slice s to XCDs {2s,2s+1} via the blockIdx%8 round-robin mapping
// (each XCD of the pair takes half the dst nodes). Random traffic becomes
// L2-hits; fabric becomes streaming (slice warm + col re-reads). FC head is
// feature-separable -> per-slice partial dots + tiny k_head sum. GEMM A-read
// and y2-write remapped to slice-major (contiguous, same cost).
// If %8->XCD mapping is wrong: perf ~flat (experiment falsifies pinning).
// CSR: two-level bucket (r8), col = src*32 byte offsets. GEMMs: split-bf16
// MFMA (r6/7), fp16 operand rows (r9).

constexpr int NN = 100000;
constexpr int NE = 1600000;
constexpr int D0 = 64;   // input dim
constexpr int D1 = 128;  // hidden 1
constexpr int D2 = 64;   // hidden 2
constexpr int NB = (NN + 255) / 256;  // 391 buckets
constexpr int TILE = 8192;            // edges per k_part/k_bcount block
constexpr int H1STRIDE = 132;         // h1 LDS row stride (u32)
constexpr int NH = NN / 2;            // 50000 nodes per XCD-half

typedef unsigned short u16;
typedef unsigned int u32;
typedef __attribute__((ext_vector_type(8))) short short8;  // 8 bf16 (4 VGPR)
typedef __attribute__((ext_vector_type(4))) float f32x4;
typedef _Float16 h4 __attribute__((ext_vector_type(4)));   // 4 fp16 = 8 B

// ---------------- CSR build ----------------

__global__ __launch_bounds__(256) void k_zero_b(int* __restrict__ g) {
    int i = blockIdx.x * 256 + threadIdx.x;
    if (i < 512) g[i] = 0;
}

// per-tile LDS histogram of dst-buckets -> global bucket counts
__global__ __launch_bounds__(256) void k_bcount(const int* __restrict__ dst,
                                                int* __restrict__ gbcnt) {
    __shared__ int cnt_s[NB];
    int tid = threadIdx.x;
    int e0 = blockIdx.x * TILE;
    int ecnt = NE - e0 < TILE ? NE - e0 : TILE;
    for (int i = tid; i < NB; i += 256) cnt_s[i] = 0;
    __syncthreads();
    for (int i = tid; i < ecnt; i += 256)
        atomicAdd(&cnt_s[dst[e0 + i] >> 8], 1);
    __syncthreads();
    for (int i = tid; i < NB; i += 256) {
        int c = cnt_s[i];
        if (c) atomicAdd(&gbcnt[i], c);
    }
}

// scan 391 bucket counts -> bucket bases (bsum, bsum[NB]=NE) + part cursors
__global__ __launch_bounds__(512) void k_scan_bsum(const int* __restrict__ gbcnt,
                                                   int* __restrict__ bsum,
                                                   int* __restrict__ gcur) {
    __shared__ int s[512];
    int tid = threadIdx.x;
    int v = (tid < NB) ? gbcnt[tid] : 0;
    s[tid] = v;
    __syncthreads();
#pragma unroll
    for (int off = 1; off < 512; off <<= 1) {
        int t = (tid >= off) ? s[tid - off] : 0;
        __syncthreads();
        s[tid] += t;
        __syncthreads();
    }
    int ex = s[tid] - v;  // exclusive scan
    if (tid <= NB) bsum[tid] = ex;   // bsum[NB] == NE
    if (tid < NB) gcur[tid] = ex;
}

// ---- partition edges into dst-buckets, packed (dl<<24)|src ----
__global__ __launch_bounds__(256) void k_part(const int* __restrict__ src,
                                              const int* __restrict__ dst,
                                              int* __restrict__ gcur,
                                              unsigned* __restrict__ packed) {
    __shared__ int cnt_s[NB];
    __shared__ int gbase_s[NB];
    __shared__ int cur_s[NB];
    int tid = threadIdx.x;
    int e0 = blockIdx.x * TILE;
    int ecnt = NE - e0 < TILE ? NE - e0 : TILE;
    for (int i = tid; i < NB; i += 256) cnt_s[i] = 0;
    __syncthreads();
    for (int i = tid; i < ecnt; i += 256)
        atomicAdd(&cnt_s[dst[e0 + i] >> 8], 1);
    __syncthreads();
    for (int i = tid; i < NB; i += 256) {
        int c = cnt_s[i];
        gbase_s[i] = c ? atomicAdd(&gcur[i], c) : 0;
        cur_s[i] = 0;
    }
    __syncthreads();
    for (int i = tid; i < ecnt; i += 256) {
        int d = dst[e0 + i];
        int s = src[e0 + i];
        int b = d >> 8;
        int slot = atomicAdd(&cur_s[b], 1);
        packed[gbase_s[b] + slot] = ((unsigned)(d & 255) << 24) | (unsigned)s;
    }
}

// ---- one block per bucket: node histogram -> dinv + rowptr, scatter col ----
// col stores BYTE offsets (src*32): slice tables are 32 B/row.
__global__ __launch_bounds__(256) void k_bucket(const int* __restrict__ bsum,
                                                const unsigned* __restrict__ packed,
                                                int* __restrict__ rowptr,
                                                float* __restrict__ dinv,
                                                int* __restrict__ col) {
    __shared__ int hist[256];
    __shared__ int s[256];
    __shared__ int cur[256];
    int b = blockIdx.x;
    int tid = threadIdx.x;
    int e0 = bsum[b], e1 = bsum[b + 1];
    hist[tid] = 0;
    __syncthreads();
    for (int e = e0 + tid; e < e1; e += 256)
        atomicAdd(&hist[packed[e] >> 24], 1);
    __syncthreads();
    int v = hist[tid];
    int n = (b << 8) + tid;
    if (n < NN) dinv[n] = rsqrtf((float)(v + 1));
    // exclusive scan of per-node counts
    s[tid] = v;
    __syncthreads();
#pragma unroll
    for (int off = 1; off < 256; off <<= 1) {
        int t = (tid >= off) ? s[tid - off] : 0;
        __syncthreads();
        s[tid] += t;
        __syncthreads();
    }
    int base = e0 + s[tid] - v;
    if (n <= NN) rowptr[n] = base;   // n==NN (last bucket) lands on e1==NE
    cur[tid] = base;
    __syncthreads();
    for (int e = e0 + tid; e < e1; e += 256) {
        unsigned p = packed[e];
        int pos = atomicAdd(&cur[p >> 24], 1);
        col[pos] = (int)((p & 0xFFFFFFu) << 5);  // src * 32 byte offset
    }
}

// ---------------- helpers ----------------

__device__ __forceinline__ float4 scale4(const float4& a, float s) {
    return float4{a.x * s, a.y * s, a.z * s, a.w * s};
}

// add 8 fp16 (uint4) into two float4 accumulators
__device__ __forceinline__ void addh8(float4& a, float4& b, uint4 u) {
    h4 h0 = *(h4*)&u.x;   // u.x,u.y
    h4 h1 = *(h4*)&u.z;   // u.z,u.w
    a.x += (float)h0[0]; a.y += (float)h0[1]; a.z += (float)h0[2]; a.w += (float)h0[3];
    b.x += (float)h1[0]; b.y += (float)h1[1]; b.z += (float)h1[2]; b.w += (float)h1[3];
}

__device__ __forceinline__ uint2 packh4(const float4& v) {
    h4 h;
    h[0] = (_Float16)v.x; h[1] = (_Float16)v.y;
    h[2] = (_Float16)v.z; h[3] = (_Float16)v.w;
    return *(uint2*)&h;
}

__device__ __forceinline__ void xor_reduce8(float4& a, float4& b, int mask) {
    a.x += __shfl_xor(a.x, mask, 64);
    a.y += __shfl_xor(a.y, mask, 64);
    a.z += __shfl_xor(a.z, mask, 64);
    a.w += __shfl_xor(a.w, mask, 64);
    b.x += __shfl_xor(b.x, mask, 64);
    b.y += __shfl_xor(b.y, mask, 64);
    b.z += __shfl_xor(b.z, mask, 64);
    b.w += __shfl_xor(b.w, mask, 64);
}

// bf16 RNE conversion + back
__device__ __forceinline__ u16 f2bf(float f) {
    u32 u = __float_as_uint(f);
    return (u16)((u + 0x7fffu + ((u >> 16) & 1u)) >> 16);
}
__device__ __forceinline__ float bf2f(u16 h) {
    return __uint_as_float(((u32)h) << 16);
}

// ---------------- prescale: xs slices = fp16(x * dinv) ----------------
// xs layout: [4 slices][NN][16 fp16] (32 B rows)
__global__ __launch_bounds__(256) void k_prescale(const float* __restrict__ x,
                                                  const float* __restrict__ dinv,
                                                  u16* __restrict__ xs) {
    int i = blockIdx.x * 256 + threadIdx.x;  // float4 chunk index
    if (i >= NN * 16) return;
    int n = i >> 4;
    int k4 = i & 15;           // 4-feature group 0..15
    int q = k4 >> 2;           // slice 0..3
    float di = dinv[n];
    uint2 v = packh4(scale4(((const float4*)x)[i], di));
    ((uint2*)xs)[((size_t)q * NN + n) * 4 + (k4 & 3)] = v;
}

// ---------------- layer-1 sliced gather ----------------
// Slice s pinned to XCDs {2s,2s+1} via blockIdx%8; each XCD takes one node
// half. Lane map: node=lane>>3 (8/wave), es=(lane>>1)&3, half=lane&1 (16B).
// agg layout: [4][NN][16] f32.
__global__ __launch_bounds__(256) void k_gather1s(const int* __restrict__ rowptr,
                                                  const int* __restrict__ colb,
                                                  const u16* __restrict__ xs,
                                                  const float* __restrict__ dinv,
                                                  float* __restrict__ agg) {
    int bid = blockIdx.x;
    int sh = bid & 7;
    int s = sh >> 1, h = sh & 1;
    int tid = threadIdx.x;
    int lane = tid & 63;
    int wv = tid >> 6;
    int n = h * NH + (bid >> 3) * 32 + wv * 8 + (lane >> 3);
    if (n >= (h + 1) * NH) return;
    int half = lane & 1;
    int es = (lane >> 1) & 3;
    int r0 = rowptr[n], r1 = rowptr[n + 1];
    const char* base = (const char*)xs + (size_t)s * NN * 32 + half * 16;
    float4 a{0, 0, 0, 0}, b{0, 0, 0, 0};
    if (es == 0) addh8(a, b, *(const uint4*)(base + (size_t)n * 32));  // self loop
    int e = r0 + es;
    for (; e + 4 < r1; e += 8) {
        int c0 = colb[e];
        int c1 = colb[e + 4];
        uint4 v0 = *(const uint4*)(base + c0);
        uint4 v1 = *(const uint4*)(base + c1);
        addh8(a, b, v0);
        addh8(a, b, v1);
    }
    for (; e < r1; e += 4)
        addh8(a, b, *(const uint4*)(base + colb[e]));
    xor_reduce8(a, b, 2);
    xor_reduce8(a, b, 4);
    if (es == 0) {
        float di = dinv[n];
        float* ag = agg + ((size_t)s * NN + n) * 16 + half * 8;
        *(float4*)ag = scale4(a, di);
        *(float4*)(ag + 4) = scale4(b, di);
    }
}

// ---------------- weight pre-split into MFMA B-fragment order ----------------
// B-fragment (16x16x32 bf16): lane l holds B[k][col], col=l&15, k=(l>>4)*8+j.
// W1 frags: [(s*8+t)*64 + l]*8 + j  (s: k-step 0..1, t: n-tile 0..7)
// W2 frags: [(s*4+t)*64 + l]*8 + j  (s: k-step 0..3, t: n-tile 0..3)
__global__ __launch_bounds__(256) void k_splitW(const float* __restrict__ W1,
                                                const float* __restrict__ W2,
                                                u16* __restrict__ W1h, u16* __restrict__ W1l,
                                                u16* __restrict__ W2h, u16* __restrict__ W2l) {
    int i = blockIdx.x * 256 + threadIdx.x;  // 0..8191
    if (i >= 8192) return;
    int j = i & 7;
    int l = (i >> 3) & 63;
    int ts = i >> 9;                 // 0..15
    int kf = ((l >> 4) << 3) + j;    // k within 32-step
    int cl = l & 15;
    {   // W1 [64][128]: ts = s*8 + t
        int s = ts >> 3, t = ts & 7;
        float w = W1[(s * 32 + kf) * D1 + t * 16 + cl];
        u16 h = f2bf(w);
        W1h[i] = h;
        W1l[i] = f2bf(w - bf2f(h));
    }
    {   // W2 [128][64]: ts = s*4 + t
        int s = ts >> 2, t = ts & 3;
        float w = W2[(s * 32 + kf) * D2 + t * 16 + cl];
        u16 h = f2bf(w);
        W2h[i] = h;
        W2l[i] = f2bf(w - bf2f(h));
    }
}

// ---------------- fused GEMM1 + GEMM2 via split-bf16 MFMA ----------------
// h1 = relu(agg @ W1 + b1)   (64 -> 128, packed hi/lo bf16 in LDS)
// y2 slices = fp16((h1 @ W2) * dinv)  (128 -> 64), layout [4][NN][16]
// agg read is slice-major: k = q*16 + c  ->  agg[(q*NN+n)*16 + c].
__global__ __launch_bounds__(256) void k_gemm12(const float* __restrict__ agg,
                                                const u16* __restrict__ W1h,
                                                const u16* __restrict__ W1l,
                                                const float* __restrict__ b1,
                                                const u16* __restrict__ W2h,
                                                const u16* __restrict__ W2l,
                                                const float* __restrict__ dinv,
                                                u16* __restrict__ y2) {
    __shared__ u32 h1s[64 * H1STRIDE];  // packed (hi | lo<<16), 33.8 KB
    int tid = threadIdx.x;
    int l = tid & 63;
    int wv = tid >> 6;
    int n_base = blockIdx.x * 64;
    int row_a = l & 15;           // A-operand row within 16-tile
    int kg = (l >> 4) << 3;       // k offset within 32-step: 0,8,16,24
    int crow = (l >> 4) * 4;      // C/D row base: (lane>>4)*4

    // ---- phase A: h1 = relu(agg @ W1 + b1) ----
    short8 Ah[2], Al[2];
#pragma unroll
    for (int s = 0; s < 2; ++s) {
        int an = n_base + wv * 16 + row_a;
        if (an >= NN) an = NN - 1;  // clamp: dup rows, outputs discarded
        int q = (s * 32 + kg) >> 4;      // agg slice
        int off = kg & 8;                // col offset within slice
        const float* ap = agg + ((size_t)q * NN + an) * 16 + off;
        f32x4 v0 = *(const f32x4*)ap;
        f32x4 v1 = *(const f32x4*)(ap + 4);
#pragma unroll
        for (int j = 0; j < 4; ++j) {
            u16 h0 = f2bf(v0[j]);
            Ah[s][j] = (short)h0;
            Al[s][j] = (short)f2bf(v0[j] - bf2f(h0));
            u16 h1b = f2bf(v1[j]);
            Ah[s][j + 4] = (short)h1b;
            Al[s][j + 4] = (short)f2bf(v1[j] - bf2f(h1b));
        }
    }
#pragma unroll
    for (int t = 0; t < 8; ++t) {
        f32x4 acc = {0.f, 0.f, 0.f, 0.f};
#pragma unroll
        for (int s = 0; s < 2; ++s) {
            short8 Bh = *(const short8*)(W1h + ((size_t)(s * 8 + t) * 64 + l) * 8);
            short8 Bl = *(const short8*)(W1l + ((size_t)(s * 8 + t) * 64 + l) * 8);
            acc = __builtin_amdgcn_mfma_f32_16x16x32_bf16(Ah[s], Bh, acc, 0, 0, 0);
            acc = __builtin_amdgcn_mfma_f32_16x16x32_bf16(Ah[s], Bl, acc, 0, 0, 0);
            acc = __builtin_amdgcn_mfma_f32_16x16x32_bf16(Al[s], Bh, acc, 0, 0, 0);
        }
        // epilogue: +b1, relu, split-pack to LDS (C/D: row=(l>>4)*4+r, col=l&15)
        float bb = b1[t * 16 + (l & 15)];
        int kcol = t * 16 + (l & 15);  // h1 feature index = GEMM2 k
#pragma unroll
        for (int r = 0; r < 4; ++r) {
            int row = wv * 16 + crow + r;  // node row in 64-tile
            float v = fmaxf(acc[r] + bb, 0.f);
            u16 h = f2bf(v);
            u16 lo = f2bf(v - bf2f(h));
            h1s[row * H1STRIDE + kcol] = (u32)h | ((u32)lo << 16);
        }
    }
    __syncthreads();

    // ---- phase B: y2 slices = fp16((h1 @ W2) * dinv) ----
    short8 A2h[4], A2l[4];
#pragma unroll
    for (int s = 0; s < 4; ++s) {
        int row = wv * 16 + row_a;
        const u32* hp = &h1s[row * H1STRIDE + s * 32 + kg];
        uint4 p0 = *(const uint4*)hp;
        uint4 p1 = *(const uint4*)(hp + 4);
        u32 pv[8] = {p0.x, p0.y, p0.z, p0.w, p1.x, p1.y, p1.z, p1.w};
#pragma unroll
        for (int j = 0; j < 8; ++j) {
            A2h[s][j] = (short)(pv[j] & 0xffffu);
            A2l[s][j] = (short)(pv[j] >> 16);
        }
    }
#pragma unroll
    for (int t = 0; t < 4; ++t) {
        f32x4 acc = {0.f, 0.f, 0.f, 0.f};
#pragma unroll
        for (int s = 0; s < 4; ++s) {
            short8 Bh = *(const short8*)(W2h + ((size_t)(s * 4 + t) * 64 + l) * 8);
            short8 Bl = *(const short8*)(W2l + ((size_t)(s * 4 + t) * 64 + l) * 8);
            acc = __builtin_amdgcn_mfma_f32_16x16x32_bf16(A2h[s], Bh, acc, 0, 0, 0);
            acc = __builtin_amdgcn_mfma_f32_16x16x32_bf16(A2h[s], Bl, acc, 0, 0, 0);
            acc = __builtin_amdgcn_mfma_f32_16x16x32_bf16(A2l[s], Bh, acc, 0, 0, 0);
        }
        // t == 16-feature slice of y2
#pragma unroll
        for (int r = 0; r < 4; ++r) {
            int n = n_base + wv * 16 + crow + r;
            if (n < NN) {
                _Float16 hf = (_Float16)(acc[r] * dinv[n]);
                y2[((size_t)t * NN + n) * 16 + (l & 15)] = *(u16*)&hf;
            }
        }
    }
}

// ---------------- layer-2 sliced gather + per-slice partial FC head ----------------
// partial[s][n] = sum_{c in slice s} relu((self+sum neigh)*di + b2)[c] * Wfc[c]
__global__ __launch_bounds__(256) void k_gather2s(const int* __restrict__ rowptr,
                                                  const int* __restrict__ colb,
                                                  const u16* __restrict__ y2,
                                                  const float* __restrict__ dinv,
                                                  const float* __restrict__ b2,
                                                  const float* __restrict__ Wfc,
                                                  float* __restrict__ partial) {
    int bid = blockIdx.x;
    int sh = bid & 7;
    int s = sh >> 1, h = sh & 1;
    int tid = threadIdx.x;
    int lane = tid & 63;
    int wv = tid >> 6;
    int n = h * NH + (bid >> 3) * 32 + wv * 8 + (lane >> 3);
    if (n >= (h + 1) * NH) return;
    int half = lane & 1;
    int es = (lane >> 1) & 3;
    int r0 = rowptr[n], r1 = rowptr[n + 1];
    const char* base = (const char*)y2 + (size_t)s * NN * 32 + half * 16;
    float4 a{0, 0, 0, 0}, b{0, 0, 0, 0};
    if (es == 0) addh8(a, b, *(const uint4*)(base + (size_t)n * 32));  // self loop
    int e = r0 + es;
    for (; e + 4 < r1; e += 8) {
        int c0 = colb[e];
        int c1 = colb[e + 4];
        uint4 v0 = *(const uint4*)(base + c0);
        uint4 v1 = *(const uint4*)(base + c1);
        addh8(a, b, v0);
        addh8(a, b, v1);
    }
    for (; e < r1; e += 4)
        addh8(a, b, *(const uint4*)(base + colb[e]));
    xor_reduce8(a, b, 2);
    xor_reduce8(a, b, 4);
    // lanes es==0 hold the 8-feature sums for (slice s, half)
    float di = dinv[n];
    int fo = s * 16 + half * 8;
    float4 b0 = *(const float4*)(b2 + fo);
    float4 b1v = *(const float4*)(b2 + fo + 4);
    float4 w0 = *(const float4*)(Wfc + fo);
    float4 w1 = *(const float4*)(Wfc + fo + 4);
    float p = fmaxf(fmaf(a.x, di, b0.x), 0.f) * w0.x
            + fmaxf(fmaf(a.y, di, b0.y), 0.f) * w0.y
            + fmaxf(fmaf(a.z, di, b0.z), 0.f) * w0.z
            + fmaxf(fmaf(a.w, di, b0.w), 0.f) * w0.w
            + fmaxf(fmaf(b.x, di, b1v.x), 0.f) * w1.x
            + fmaxf(fmaf(b.y, di, b1v.y), 0.f) * w1.y
            + fmaxf(fmaf(b.z, di, b1v.z), 0.f) * w1.z
            + fmaxf(fmaf(b.w, di, b1v.w), 0.f) * w1.w;
    p += __shfl_xor(p, 1, 64);  // combine halves
    if ((lane & 7) == 0 && es == 0) partial[(size_t)s * NN + n] = p;
}

// ---------------- head: sum 4 slice partials + bfc ----------------
__global__ __launch_bounds__(256) void k_head(const float* __restrict__ partial,
                                              const float* __restrict__ bfc,
                                              float* __restrict__ out) {
    int i = blockIdx.x * 256 + threadIdx.x;
    if (i >= NN) return;
    out[i] = partial[i] + partial[NN + i] + partial[2 * NN + i]
           + partial[3 * NN + i] + bfc[0];
}

extern "C" void kernel_launch(void* const* d_in, const int* in_sizes, int n_in,
                              void* d_out, int out_size, void* d_ws, size_t ws_size,
                              hipStream_t stream) {
    const float* x   = (const float*)d_in[0];
    const int*   ei  = (const int*)d_in[1];   // [2, E] int
    const float* W1  = (const float*)d_in[2];
    const float* b1  = (const float*)d_in[3];
    const float* W2  = (const float*)d_in[4];
    const float* b2  = (const float*)d_in[5];
    const float* Wfc = (const float*)d_in[6];
    const float* bfc = (const float*)d_in[7];
    float* out = (float*)d_out;

    const int* src = ei;
    const int* dst = ei + NE;

    char* ws = (char*)d_ws;
    size_t o = 0;
    auto alloc = [&](size_t bytes) { char* p = ws + o; o += (bytes + 255) & ~size_t(255); return p; };
    int*   scratch = (int*)alloc(NN * 4);      // 400 KB: gbcnt + W-split buffers
    int*   rowptr = (int*)alloc((NN + 1) * 4);
    int*   bsum   = (int*)alloc(512 * 4);
    int*   gcur   = (int*)alloc(NB * 4);
    float* dinv   = (float*)alloc(NN * 4);
    int*   col    = (int*)alloc((size_t)NE * 4);
    u16*   xs     = (u16*)alloc((size_t)NN * D0 * 2);    // 12.8 MB fp16 (4 slices)
    float* agg1x  = (float*)alloc((size_t)NN * D0 * 4);  // 25.6 MB fp32 (4 slices)
    u16*   y2     = (u16*)alloc((size_t)NN * D2 * 2);    // 12.8 MB fp16 (4 slices)
    float* partial= (float*)alloc((size_t)NN * 4 * 4);   // 1.6 MB
    unsigned* packed = (unsigned*)agg1x;  // dead before k_gather1s writes agg
    // carve scratch: bucket counts (512 ints) then the 4 x 16 KB weight splits
    int* gbcnt = scratch;
    u16* W1h = (u16*)(scratch + 512);
    u16* W1l = W1h + 8192;
    u16* W2h = W1l + 8192;
    u16* W2l = W2h + 8192;

    const int NT = (NE + TILE - 1) / TILE;  // 196 tiles
    const int GB = 8 * ((NH + 31) / 32);    // 12504 blocks: slice-pinned gathers

    k_zero_b    <<<2, 256, 0, stream>>>(gbcnt);
    k_splitW    <<<32, 256, 0, stream>>>(W1, W2, W1h, W1l, W2h, W2l);
    k_bcount    <<<NT, 256, 0, stream>>>(dst, gbcnt);
    k_scan_bsum <<<1, 512, 0, stream>>>(gbcnt, bsum, gcur);
    k_part      <<<NT, 256, 0, stream>>>(src, dst, gcur, packed);
    k_bucket    <<<NB, 256, 0, stream>>>(bsum, packed, rowptr, dinv, col);
    k_prescale  <<<(NN * 16 + 255) / 256, 256, 0, stream>>>(x, dinv, xs);

    k_gather1s  <<<GB, 256, 0, stream>>>(rowptr, col, xs, dinv, agg1x);
    k_gemm12    <<<(NN + 63) / 64, 256, 0, stream>>>(agg1x, W1h, W1l, b1, W2h, W2l, dinv, y2);
    k_gather2s  <<<GB, 256, 0, stream>>>(rowptr, col, y2, dinv, b2, Wfc, partial);
    k_head      <<<(NN + 255) / 256, 256, 0, stream>>>(partial, bfc, out);
}